// Round 8
// baseline (126.984 us; speedup 1.0000x reference)
//
#include <hip/hip_runtime.h>

// GPSA bf16-MFMA v15. B=64, N=300, C=256, H=8, hd=32.
// v14 -> v15: fused GEMM phase restructured to kill the per-kt staging drains.
//  - W ([96][256] bf16, 49.2 KB) staged into LDS ONCE at kernel start
//    (pre-swizzled slot = c ^ (row&31) so frag reads are ~2-way conflicted).
//  - X fragments load DIRECTLY from global x_bf (single 16B dwordx4 per frag,
//    L2-resident via XCD-colocated h-blocks). No Xs LDS buffer.
//  - GEMM barriers 8 -> 2 (post-W-stage, pre-overlay). X loads freely
//    pipelined by the compiler across the fully unrolled K loop.
//  - Numerics bit-identical to v14 (same values, same accumulation order).
// K0 prep: x->x_bf linear [64][304][256] (rows 300..303 zero); gpos softmax;
//          Wf[h][96][32 slots] full-K pre-swizzled; wproj_t (unchanged).
// K4 proj: byte-identical to v14.

#define NSEQ 300
#define HEADS 8
#define HD 32

typedef short v8s __attribute__((ext_vector_type(8)));
typedef float v4f __attribute__((ext_vector_type(4)));
typedef unsigned int v4u __attribute__((ext_vector_type(4)));

__device__ __forceinline__ ushort f2bf(float f) {
    unsigned u = __float_as_uint(f);
    u = (u + 0x7FFFu + ((u >> 16) & 1u)) >> 16;   // RNE
    return (ushort)u;
}

// pack two fp32 -> packed bf16x2 (lo=a, hi=b) via v_perm
__device__ __forceinline__ unsigned pk2bf(float a, float b) {
    unsigned ua = __float_as_uint(a), ub = __float_as_uint(b);
    ua += 0x7FFFu + ((ua >> 16) & 1u);
    ub += 0x7FFFu + ((ub >> 16) & 1u);
    return __builtin_amdgcn_perm(ub, ua, 0x07060302);  // [ua.hi16 | ub.hi16]
}

// single-instruction RNE pack (lo=a, hi=b)
__device__ __forceinline__ unsigned cvtpk(float a, float b) {
    unsigned r;
    asm("v_cvt_pk_bf16_f32 %0, %1, %2" : "=v"(r) : "v"(a), "v"(b));
    return r;
}

__device__ __forceinline__ float fexp2(float x) {
    float r; asm("v_exp_f32 %0, %1" : "=v"(r) : "v"(x)); return r;
}

// async global->LDS DMA, 16B per lane
__device__ __forceinline__ void gl_lds16(const ushort* g, ushort* l) {
    __builtin_amdgcn_global_load_lds(
        (const __attribute__((address_space(1))) void*)g,
        (__attribute__((address_space(3))) void*)l, 16, 0, 0);
}

// ---------------- K0: prep = x->bf16 + gpos softmax + weight swizzle ----------------
// blocks 0..2431: x_bf | 2432..3039: gpos | 3040..3135: Wf | 3136..3167: wproj_t
__global__ __launch_bounds__(256) void prep_kernel(
    const float* __restrict__ x,
    const float* __restrict__ Wqk, const float* __restrict__ Wv,
    const float* __restrict__ Wproj, const float* __restrict__ Wpos,
    const float* __restrict__ bpos, const float* __restrict__ gating,
    ushort* __restrict__ x_bf, ushort* __restrict__ Wf,
    ushort* __restrict__ wproj_t, ushort* __restrict__ gpos)
{
    int bid = blockIdx.x, tid = threadIdx.x;
    if (bid < 2432) {                           // x -> x_bf [64][304][256], zero-pad
        int idx = bid * 256 + tid;              // 0..622591
        int c8 = idx & 31;
        int mrow = idx >> 5;                    // b*304 + r
        unsigned b = (unsigned)mrow / 304u;
        int r = mrow - (int)b * 304;
        v4u pk = {0u, 0u, 0u, 0u};
        if (r < 300) {
            const float* src = x + ((size_t)b * 300 + r) * 256 + c8 * 8;
            float4 f0 = *(const float4*)src;
            float4 f1 = *(const float4*)(src + 4);
            pk = (v4u){pk2bf(f0.x, f0.y), pk2bf(f0.z, f0.w),
                       pk2bf(f1.x, f1.y), pk2bf(f1.z, f1.w)};
        }
        *(v4u*)&x_bf[(size_t)mrow * 256 + c8 * 8] = pk;
        return;
    }
    if (bid < 3040) {                           // gated positional softmax
        int sub = bid - 2432;
        int h = sub / 76;
        int i = (sub % 76) * 4 + (tid >> 6);    // row 0..303
        int lane = tid & 63;
        ushort* gr = gpos + ((size_t)h * 304 + i) * 304;
        if (i >= NSEQ) {
#pragma unroll
            for (int t = 0; t < 5; ++t) {
                int j = lane + 64 * t;
                if (j < 304) gr[j] = 0;
            }
            return;
        }
        float w0 = Wpos[h * 3 + 0], w2 = Wpos[h * 3 + 2], bb = bpos[h];
        float g = 1.f / (1.f + __expf(-gating[h]));
        float sv[5]; float m2 = -1e30f;
#pragma unroll
        for (int t = 0; t < 5; ++t) {
            int j = lane + 64 * t;
            float d = (float)(j - i);
            float lg = fmaf(w2, d * d, fmaf(w0, d, bb));
            sv[t] = (j < NSEQ) ? lg : -1e30f;   // logits +-7000: max-sub required
            m2 = fmaxf(m2, sv[t]);
        }
#pragma unroll
        for (int off = 32; off > 0; off >>= 1) m2 = fmaxf(m2, __shfl_xor(m2, off));
        float sum = 0.f;
#pragma unroll
        for (int t = 0; t < 5; ++t) { sv[t] = __expf(sv[t] - m2); sum += sv[t]; }
#pragma unroll
        for (int off = 32; off > 0; off >>= 1) sum += __shfl_xor(sum, off);
        float gi = g / sum;
#pragma unroll
        for (int t = 0; t < 5; ++t) {
            int j = lane + 64 * t;
            if (j < NSEQ) gr[j] = f2bf(sv[t] * gi);
            else if (j < 304) gr[j] = 0;
        }
        return;
    }
    if (bid < 3136) {                           // Wf: [h][96 rows][32 slots] full-K
        int idx = (bid - 3040) * 256 + tid;     // 0..24575
        int s = idx & 31;                       // LDS slot within row
        int t = idx >> 5;                       // 0..767
        int h = t / 96;
        int wc = t - h * 96;                    // row 0..95
        int lc = s ^ (wc & 31);                 // logical chunk held at slot s
        const float* src;
        if (wc < 32)      src = Wqk + (size_t)(h * 32 + wc) * 256;
        else if (wc < 64) src = Wqk + (size_t)(256 + h * 32 + (wc - 32)) * 256;
        else              src = Wv + (size_t)(h * 32 + (wc - 64)) * 256;
        src += lc * 8;
        float4 f0 = *(const float4*)src;
        float4 f1 = *(const float4*)(src + 4);
        v4u pk = {pk2bf(f0.x, f0.y), pk2bf(f0.z, f0.w),
                  pk2bf(f1.x, f1.y), pk2bf(f1.z, f1.w)};
        *(v4u*)&Wf[((size_t)(h * 96 + wc)) * 256 + s * 8] = pk;
        return;
    }
    {                                           // wproj_t: 256 rows x 32 chunks
        int idx = (bid - 3136) * 256 + tid;     // 0..8191
        int m = idx >> 5, ck = idx & 31;
        const float* src = Wproj + (size_t)m * 256 + ck * 8;
        int rt = m >> 7, rr = m & 127, kt = ck >> 3, c = ck & 7;
        float4 f0 = *(const float4*)src;
        float4 f1 = *(const float4*)(src + 4);
        v4u pk = {pk2bf(f0.x, f0.y), pk2bf(f0.z, f0.w),
                  pk2bf(f1.x, f1.y), pk2bf(f1.z, f1.w)};
        *(v4u*)&wproj_t[((size_t)(rt * 4 + kt) * 128 + rr) * 64 + ((c ^ (rr & 7)) * 8)] = pk;
    }
}

// ---------------- K23: fused QKV GEMM + attention (512 threads, 8 waves) ----------------
// block = (b,h) with id = h*64 + b  (8 h-blocks of one b share an XCD)
__global__ __launch_bounds__(512, 4) void fused_qkv_attn(
    const ushort* __restrict__ x_bf, const ushort* __restrict__ Wf,
    const ushort* __restrict__ gpos, const float* __restrict__ gating,
    ushort* __restrict__ ot)
{
    __shared__ ushort smem[24576];     // 49152 B
    ushort* Wsh = smem;                // GEMM: [96][256] swizzled (49152 B)
    ushort* Ks = smem;                 // ATTN: [304][40] (24320 B)
    ushort* Vt = smem + 12160;         // ATTN: [32][328] (20992 B)

    int bid = blockIdx.x, b = bid & 63, h = bid >> 6;
    int tid = threadIdx.x, wave = tid >> 6, lane = tid & 63, li = lane & 15, qd = lane >> 4;

    const ushort* xbb = x_bf + (size_t)b * 304 * 256;
    const ushort* wfh = Wf + (size_t)h * 96 * 256;

    v4f acc[3][6];
#pragma unroll
    for (int i = 0; i < 3; ++i)
#pragma unroll
        for (int j = 0; j < 6; ++j) acc[i][j] = (v4f){0.f, 0.f, 0.f, 0.f};

    // -------- stage FULL W once: 3072 chunks of 16B, 6 per thread --------
#pragma unroll
    for (int s = 0; s < 6; ++s) {
        int c = s * 512 + tid;
        gl_lds16(wfh + c * 8, Wsh + c * 8);
    }
    __syncthreads();                   // single drain for all of W

    // -------- GEMM phase: q|k|v[304x96] = X[304x256] @ W[256x96] --------
    // X fragments: single global_load_dwordx4 each, straight from x_bf.
    // No barriers inside -> compiler pipelines loads across the K loop.
#pragma unroll
    for (int kt = 0; kt < 4; ++kt) {
#pragma unroll
        for (int kc = 0; kc < 2; ++kc) {
            int xoff = kt * 64 + kc * 32 + qd * 8;
            v8s ax0 = *(const v8s*)(xbb + (size_t)(wave * 16 + li) * 256 + xoff);
            v8s ax1 = *(const v8s*)(xbb + (size_t)((wave + 8) * 16 + li) * 256 + xoff);
            v8s ax2;
            if (wave < 3)              // rt = wave+16 < 19 (wave-uniform)
                ax2 = *(const v8s*)(xbb + (size_t)((wave + 16) * 16 + li) * 256 + xoff);
            int cb = kt * 8 + kc * 4 + qd;
            v8s bw[6];
#pragma unroll
            for (int ct = 0; ct < 6; ++ct) {
                int row = ct * 16 + li;
                bw[ct] = *(const v8s*)&Wsh[row * 256 + (cb ^ (row & 31)) * 8];
            }
#pragma unroll
            for (int ct = 0; ct < 6; ++ct)
                acc[0][ct] = __builtin_amdgcn_mfma_f32_16x16x32_bf16(bw[ct], ax0, acc[0][ct], 0, 0, 0);
#pragma unroll
            for (int ct = 0; ct < 6; ++ct)
                acc[1][ct] = __builtin_amdgcn_mfma_f32_16x16x32_bf16(bw[ct], ax1, acc[1][ct], 0, 0, 0);
            if (wave < 3) {
#pragma unroll
                for (int ct = 0; ct < 6; ++ct)
                    acc[2][ct] = __builtin_amdgcn_mfma_f32_16x16x32_bf16(bw[ct], ax2, acc[2][ct], 0, 0, 0);
            }
        }
    }
    __syncthreads();                   // all waves done READING Wsh

    // -------- writeback: q -> registers (cross-qd shuffle), k/v -> LDS --------
    // swapped-operand acc: C[row = rt*16+li][col = ct*16 + qd*4 + r]
    const float QSC = 0.25503486063f;          // log2(e)/sqrt(32)
    v4u q0 = {0,0,0,0}, q1 = {0,0,0,0}, q2 = {0,0,0,0};
    int srcA = ((qd & 1) << 5) + li;           // lane of qd' = (qd&1)*2
    int srcB = srcA + 16;                      // lane of qd' = (qd&1)*2 + 1
#pragma unroll
    for (int i = 0; i < 3; ++i) {
        int rt = wave + i * 8;
        if (rt < 19) {                         // wave-uniform guard
            unsigned W00 = cvtpk(acc[i][0][0] * QSC, acc[i][0][1] * QSC);
            unsigned W01 = cvtpk(acc[i][0][2] * QSC, acc[i][0][3] * QSC);
            unsigned W10 = cvtpk(acc[i][1][0] * QSC, acc[i][1][1] * QSC);
            unsigned W11 = cvtpk(acc[i][1][2] * QSC, acc[i][1][3] * QSC);
            unsigned a0 = __shfl(W00, srcA), a1 = __shfl(W01, srcA);
            unsigned a2 = __shfl(W00, srcB), a3 = __shfl(W01, srcB);
            unsigned b0 = __shfl(W10, srcA), b1 = __shfl(W11, srcA);
            unsigned b2 = __shfl(W10, srcB), b3 = __shfl(W11, srcB);
            bool hi = (qd >= 2);
            v4u qq = {hi ? b0 : a0, hi ? b1 : a1, hi ? b2 : a2, hi ? b3 : a3};
            if (i == 0) q0 = qq; else if (i == 1) q1 = qq; else q2 = qq;

            int row = rt * 16 + li;
#pragma unroll
            for (int ct = 2; ct < 4; ++ct) {   // k -> Ks[row][dim]
                uint2 wk = {cvtpk(acc[i][ct][0], acc[i][ct][1]),
                            cvtpk(acc[i][ct][2], acc[i][ct][3])};
                *(uint2*)&Ks[row * 40 + (ct - 2) * 16 + qd * 4] = wk;
            }
#pragma unroll
            for (int ct = 4; ct < 6; ++ct)     // v -> Vt[dim][row] (transposed)
#pragma unroll
                for (int r = 0; r < 4; ++r)
                    Vt[((ct - 4) * 16 + qd * 4 + r) * 328 + row] = f2bf(acc[i][ct][r]);
        }
    }
    float g = 1.f / (1.f + __expf(-gating[h]));
    float omg = 1.f - g;
    __syncthreads();

    // -------- attention phase (pair-packed loop, 2-deep gpos prefetch) --------
    const ushort* ksp0 = &Ks[li * 40 + qd * 8];
    const ushort* vtp0 = &Vt[li * 328 + qd * 4];
    const ushort* vtp1 = &Vt[(16 + li) * 328 + qd * 4];
    const v4f z4 = {0.f, 0.f, 0.f, 0.f};

#pragma unroll 1
    for (int rg = wave; rg < 19; rg += 8) {
        int i0 = rg * 16;
        // Q rows >= 300 are exact zeros (zero-padded X) -> masked at store
        v8s bq = __builtin_bit_cast(v8s, q0);
        const ushort* gp = gpos + ((size_t)h * 304 + (i0 + li)) * 304 + qd * 4;

        v4f Oe0 = z4, Oe1 = z4, Og0 = z4, Og1 = z4;
        float esum = 0.f;

        // prologue: pair-0 K/V operands + scores; gpos pairs 0 and 1 in flight
        v8s ak0 = *(const v8s*)(ksp0);
        v8s ak1 = *(const v8s*)(ksp0 + 640);
        uint2 v0a = *(const uint2*)(vtp0);
        uint2 v0b = *(const uint2*)(vtp0 + 16);
        uint2 v1a = *(const uint2*)(vtp1);
        uint2 v1b = *(const uint2*)(vtp1 + 16);
        uint2 gc0 = *(const uint2*)(gp);            // pair 0 (tiles 0,1)
        uint2 gc1 = *(const uint2*)(gp + 16);
        uint2 gn0 = *(const uint2*)(gp + 32);       // pair 1 (tiles 2,3)
        uint2 gn1 = *(const uint2*)(gp + 48);
        v4f s0n = __builtin_amdgcn_mfma_f32_16x16x32_bf16(ak0, bq, z4, 0, 0, 0);
        v4f s1n = __builtin_amdgcn_mfma_f32_16x16x32_bf16(ak1, bq, z4, 0, 0, 0);

#pragma unroll 1
        for (int p = 0; p < 9; ++p) {          // pairs (nt=2p, 2p+1), nt<=17
            v4f s0 = s0n, s1 = s1n;
            v8s b0 = __builtin_bit_cast(v8s, (v4u){v0a.x, v0a.y, v0b.x, v0b.y});
            v8s b1 = __builtin_bit_cast(v8s, (v4u){v1a.x, v1a.y, v1b.x, v1b.y});
            v8s ag = __builtin_bit_cast(v8s, (v4u){gc0.x, gc0.y, gc1.x, gc1.y});
            gc0 = gn0; gc1 = gn1;              // shift gpos pipeline
            int nt0 = 2 * p + 2;               // next pair (p=8 -> tail tile 18)
            int nt1 = (p < 8) ? nt0 + 1 : 18;
            int gt0 = (p < 7) ? 2 * p + 4 : 18;  // pair p+2 (clamp to tail)
            int gt1 = (p < 7) ? 2 * p + 5 : 18;
            ak0 = *(const v8s*)(ksp0 + nt0 * 640);
            ak1 = *(const v8s*)(ksp0 + nt1 * 640);
            v0a = *(const uint2*)(vtp0 + nt0 * 16);
            v0b = *(const uint2*)(vtp0 + nt1 * 16);
            v1a = *(const uint2*)(vtp1 + nt0 * 16);
            v1b = *(const uint2*)(vtp1 + nt1 * 16);
            gn0 = *(const uint2*)(gp + gt0 * 16);
            gn1 = *(const uint2*)(gp + gt1 * 16);
            s0n = __builtin_amdgcn_mfma_f32_16x16x32_bf16(ak0, bq, z4, 0, 0, 0);
            s1n = __builtin_amdgcn_mfma_f32_16x16x32_bf16(ak1, bq, z4, 0, 0, 0);

            float e0 = fexp2(s0[0]);           // log2(e) folded into q scale
            float e1 = fexp2(s0[1]);
            float e2 = fexp2(s0[2]);
            float e3 = fexp2(s0[3]);
            float f0 = fexp2(s1[0]);
            float f1 = fexp2(s1[1]);
            float f2 = fexp2(s1[2]);
            float f3 = fexp2(s1[3]);
            esum += ((e0 + e1) + (e2 + e3)) + ((f0 + f1) + (f2 + f3));
            v8s ae = __builtin_bit_cast(v8s, (v4u){cvtpk(e0, e1), cvtpk(e2, e3),
                                                   cvtpk(f0, f1), cvtpk(f2, f3)});
            __builtin_amdgcn_s_setprio(1);
            Oe0 = __builtin_amdgcn_mfma_f32_16x16x32_bf16(ae, b0, Oe0, 0, 0, 0);
            Oe1 = __builtin_amdgcn_mfma_f32_16x16x32_bf16(ae, b1, Oe1, 0, 0, 0);
            Og0 = __builtin_amdgcn_mfma_f32_16x16x32_bf16(ag, b0, Og0, 0, 0, 0);
            Og1 = __builtin_amdgcn_mfma_f32_16x16x32_bf16(ag, b1, Og1, 0, 0, 0);
            __builtin_amdgcn_s_setprio(0);
        }
        {   // tail tile nt=18 (j=288..303): scores in s0n; gc0 holds tile 18
            float e0 = fexp2(s0n[0]);
            float e1 = fexp2(s0n[1]);
            float e2 = fexp2(s0n[2]);
            float e3 = fexp2(s0n[3]);
            if (qd == 3) { e0 = e1 = e2 = e3 = 0.f; }   // j >= 300
            esum += (e0 + e1) + (e2 + e3);
            v8s ae = __builtin_bit_cast(v8s, (v4u){cvtpk(e0, e1), cvtpk(e2, e3), 0u, 0u});
            v8s ag = __builtin_bit_cast(v8s, (v4u){gc0.x, gc0.y, 0u, 0u});
            v8s b0 = __builtin_bit_cast(v8s, (v4u){v0a.x, v0a.y, 0u, 0u});
            v8s b1 = __builtin_bit_cast(v8s, (v4u){v1a.x, v1a.y, 0u, 0u});
            Oe0 = __builtin_amdgcn_mfma_f32_16x16x32_bf16(ae, b0, Oe0, 0, 0, 0);
            Oe1 = __builtin_amdgcn_mfma_f32_16x16x32_bf16(ae, b1, Oe1, 0, 0, 0);
            Og0 = __builtin_amdgcn_mfma_f32_16x16x32_bf16(ag, b0, Og0, 0, 0, 0);
            Og1 = __builtin_amdgcn_mfma_f32_16x16x32_bf16(ag, b1, Og1, 0, 0, 0);
        }
        esum += __shfl_xor(esum, 16);
        esum += __shfl_xor(esum, 32);          // full row sum for query i0+li
        float ps = omg / esum;                 // (skip /attn.sum: it's 1 +- 1e-6)
        float psr[4];
#pragma unroll
        for (int r = 0; r < 4; ++r) psr[r] = __shfl(ps, qd * 4 + r);
#pragma unroll
        for (int r = 0; r < 4; ++r) {
            int row = i0 + qd * 4 + r;
            if (row < NSEQ) {
                int m = b * NSEQ + row;
                int rt = m >> 7, rr = m & 127;
                int c0 = (h & 1) * 4 + (li >> 3);
                int p2 = li & 7;
                size_t tb = ((size_t)(rt * 4 + (h >> 1)) * 128 + rr) * 64;
                ot[tb + ((c0 ^ (rr & 7)) * 8) + p2] = f2bf(fmaf(psr[r], Oe0[r], Og0[r]));
                ot[tb + (((c0 + 2) ^ (rr & 7)) * 8) + p2] = f2bf(fmaf(psr[r], Oe1[r], Og1[r]));
            }
        }
        q0 = q1; q1 = q2;                      // rotate q registers (static idx)
    }
}

// ---------------- K4: output projection, BM=64, DMA staging + bias ----------------
__global__ __launch_bounds__(256, 4) void gemm_proj_mfma(
    const ushort* __restrict__ A, const ushort* __restrict__ Bw,
    const float* __restrict__ bias, float* __restrict__ out)
{
    __shared__ ushort As[64 * 64];    // 8 KB
    __shared__ ushort Bs[128 * 64];   // 16 KB
    int tid = threadIdx.x;
    int wave = tid >> 6, lane = tid & 63, li = lane & 15, qd = lane >> 4;
    int rh = wave >> 1, ch = wave & 1;
    int by = blockIdx.y;
    const ushort* gA = A + ((size_t)(by >> 1) * 4 * 128 + (by & 1) * 64) * 64;
    const ushort* gB = Bw + (size_t)blockIdx.x * 4 * 8192;

    v4f acc[2][4];
#pragma unroll
    for (int i = 0; i < 2; ++i)
#pragma unroll
        for (int j = 0; j < 4; ++j) acc[i][j] = (v4f){0.f, 0.f, 0.f, 0.f};

    for (int kt = 0; kt < 4; ++kt) {
#pragma unroll
        for (int s = 0; s < 2; ++s) {
            int cch = s * 256 + tid;
            gl_lds16(gA + (size_t)kt * 128 * 64 + cch * 8, As + cch * 8);
        }
#pragma unroll
        for (int s = 0; s < 4; ++s) {
            int cch = s * 256 + tid;
            gl_lds16(gB + (size_t)kt * 8192 + cch * 8, Bs + cch * 8);
        }
        __syncthreads();
#pragma unroll
        for (int kc = 0; kc < 64; kc += 32) {
            int cb = (kc >> 3) + qd;
            int cs = cb ^ (li & 7);
            v8s a[2], b[4];
#pragma unroll
            for (int mt = 0; mt < 2; ++mt)
                a[mt] = *(const v8s*)&As[(rh * 32 + mt * 16 + li) * 64 + cs * 8];
#pragma unroll
            for (int nt = 0; nt < 4; ++nt)
                b[nt] = *(const v8s*)&Bs[(ch * 64 + nt * 16 + li) * 64 + cs * 8];
#pragma unroll
            for (int mt = 0; mt < 2; ++mt)
#pragma unroll
                for (int nt = 0; nt < 4; ++nt)
                    acc[mt][nt] = __builtin_amdgcn_mfma_f32_16x16x32_bf16(b[nt], a[mt], acc[mt][nt], 0, 0, 0);
        }
        __syncthreads();
    }

#pragma unroll
    for (int mt = 0; mt < 2; ++mt) {
        int row = by * 64 + rh * 32 + mt * 16 + li;
#pragma unroll
        for (int nt = 0; nt < 4; ++nt) {
            int col = blockIdx.x * 128 + ch * 64 + nt * 16 + qd * 4;
            float4 bv = *(const float4*)&bias[col];
            float4 st = {acc[mt][nt][0] + bv.x, acc[mt][nt][1] + bv.y,
                         acc[mt][nt][2] + bv.z, acc[mt][nt][3] + bv.w};
            *(float4*)&out[(size_t)row * 256 + col] = st;
        }
    }
}

extern "C" void kernel_launch(void* const* d_in, const int* in_sizes, int n_in,
                              void* d_out, int out_size, void* d_ws, size_t ws_size,
                              hipStream_t stream) {
    const float* x      = (const float*)d_in[0];
    const float* Wqk    = (const float*)d_in[1];
    const float* Wv     = (const float*)d_in[2];
    const float* Wpos   = (const float*)d_in[3];
    const float* bpos   = (const float*)d_in[4];
    const float* Wproj  = (const float*)d_in[5];
    const float* bproj  = (const float*)d_in[6];
    const float* gating = (const float*)d_in[7];
    float* out = (float*)d_out;

    ushort* gpos     = (ushort*)d_ws;             // 8*304*304 = 739,328
    ushort* Wf       = gpos + 739328;             // 8*96*256 = 196,608 (swizzled)
    ushort* wproj_t  = Wf + 196608;               // 65,536 (tiled+swizzled)
    ushort* o_t      = wproj_t + 65536;           // 4,915,200 (tiled+swizzled)
    ushort* x_bf     = o_t + 4915200;             // 64*304*256 = 4,980,736

    prep_kernel<<<3168, 256, 0, stream>>>(x, Wqk, Wv, Wproj, Wpos, bpos, gating,
                                          x_bf, Wf, wproj_t, gpos);
    fused_qkv_attn<<<512, 512, 0, stream>>>(x_bf, Wf, gpos, gating, o_t);
    gemm_proj_mfma<<<dim3(2, 300), 256, 0, stream>>>(o_t, wproj_t, bproj, out);
}

// Round 9
// 124.790 us; speedup vs baseline: 1.0176x; 1.0176x over previous
//
#include <hip/hip_runtime.h>

// GPSA bf16-MFMA v16. B=64, N=300, C=256, H=8, hd=32.
// v14 (best, 122.9us) + x->bf16 conversion folded INTO the fused kernel's
// X staging (x_bf intermediate eliminated; prep shrinks 3168 -> 736 blocks).
//  - X staging per kt: each thread loads 2 float4 of raw fp32 x (swizzle
//    folded into the global COLUMN selection -> 8 consecutive lanes read a
//    permuted-but-complete 256B row segment, fully coalesced), cvt_pk to
//    bf16x2, linear ds_write_b128. Rows 300..303 zeroed in-kernel.
//  - Same RNE pack + same accumulation order as v14 -> bitwise-identical.
//  - GEMM/attention/sync structure byte-identical to v14 (the passing one).
// K0 prep: gpos softmax + Wf[h][kt][96][64] swizzle + wproj_t (736 blocks).
// K4 proj: byte-identical to v14.

#define NSEQ 300
#define HEADS 8
#define HD 32

typedef short v8s __attribute__((ext_vector_type(8)));
typedef float v4f __attribute__((ext_vector_type(4)));
typedef unsigned int v4u __attribute__((ext_vector_type(4)));

__device__ __forceinline__ ushort f2bf(float f) {
    unsigned u = __float_as_uint(f);
    u = (u + 0x7FFFu + ((u >> 16) & 1u)) >> 16;   // RNE
    return (ushort)u;
}

// pack two fp32 -> packed bf16x2 (lo=a, hi=b) via v_perm
__device__ __forceinline__ unsigned pk2bf(float a, float b) {
    unsigned ua = __float_as_uint(a), ub = __float_as_uint(b);
    ua += 0x7FFFu + ((ua >> 16) & 1u);
    ub += 0x7FFFu + ((ub >> 16) & 1u);
    return __builtin_amdgcn_perm(ub, ua, 0x07060302);  // [ua.hi16 | ub.hi16]
}

// single-instruction RNE pack (lo=a, hi=b)
__device__ __forceinline__ unsigned cvtpk(float a, float b) {
    unsigned r;
    asm("v_cvt_pk_bf16_f32 %0, %1, %2" : "=v"(r) : "v"(a), "v"(b));
    return r;
}

__device__ __forceinline__ float fexp2(float x) {
    float r; asm("v_exp_f32 %0, %1" : "=v"(r) : "v"(x)); return r;
}

// async global->LDS DMA, 16B per lane
__device__ __forceinline__ void gl_lds16(const ushort* g, ushort* l) {
    __builtin_amdgcn_global_load_lds(
        (const __attribute__((address_space(1))) void*)g,
        (__attribute__((address_space(3))) void*)l, 16, 0, 0);
}

// ---------------- K0: prep = gpos softmax + weight swizzle (736 blocks) ----------------
// blocks 0..607: gpos rows | 608..703: Wf (qkv weights) | 704..735: wproj_t
__global__ __launch_bounds__(256) void prep_kernel(
    const float* __restrict__ Wqk, const float* __restrict__ Wv,
    const float* __restrict__ Wproj, const float* __restrict__ Wpos,
    const float* __restrict__ bpos, const float* __restrict__ gating,
    ushort* __restrict__ Wf, ushort* __restrict__ wproj_t,
    ushort* __restrict__ gpos)
{
    int bid = blockIdx.x, tid = threadIdx.x;
    if (bid < 608) {                            // gated positional softmax
        int sub = bid;
        int h = sub / 76;
        int i = (sub % 76) * 4 + (tid >> 6);    // row 0..303
        int lane = tid & 63;
        ushort* gr = gpos + ((size_t)h * 304 + i) * 304;
        if (i >= NSEQ) {
#pragma unroll
            for (int t = 0; t < 5; ++t) {
                int j = lane + 64 * t;
                if (j < 304) gr[j] = 0;
            }
            return;
        }
        float w0 = Wpos[h * 3 + 0], w2 = Wpos[h * 3 + 2], bb = bpos[h];
        float g = 1.f / (1.f + __expf(-gating[h]));
        float sv[5]; float m2 = -1e30f;
#pragma unroll
        for (int t = 0; t < 5; ++t) {
            int j = lane + 64 * t;
            float d = (float)(j - i);
            float lg = fmaf(w2, d * d, fmaf(w0, d, bb));
            sv[t] = (j < NSEQ) ? lg : -1e30f;   // logits +-7000: max-sub required
            m2 = fmaxf(m2, sv[t]);
        }
#pragma unroll
        for (int off = 32; off > 0; off >>= 1) m2 = fmaxf(m2, __shfl_xor(m2, off));
        float sum = 0.f;
#pragma unroll
        for (int t = 0; t < 5; ++t) { sv[t] = __expf(sv[t] - m2); sum += sv[t]; }
#pragma unroll
        for (int off = 32; off > 0; off >>= 1) sum += __shfl_xor(sum, off);
        float gi = g / sum;
#pragma unroll
        for (int t = 0; t < 5; ++t) {
            int j = lane + 64 * t;
            if (j < NSEQ) gr[j] = f2bf(sv[t] * gi);
            else if (j < 304) gr[j] = 0;
        }
        return;
    }
    if (bid < 704) {                            // Wf: 8h x 4kt x 96 rows x 8 chunks
        int idx = (bid - 608) * 256 + tid;      // 0..24575
        int c = idx & 7;
        int t = idx >> 3;                       // 0..3071
        int hk = t / 96;                        // h*4+kt
        int wc = t - hk * 96;                   // 0..95
        int h = hk >> 2, kt = hk & 3;
        const float* src;
        if (wc < 32)      src = Wqk + (size_t)(h * 32 + wc) * 256;
        else if (wc < 64) src = Wqk + (size_t)(256 + h * 32 + (wc - 32)) * 256;
        else              src = Wv + (size_t)(h * 32 + (wc - 64)) * 256;
        src += kt * 64 + c * 8;
        float4 f0 = *(const float4*)src;
        float4 f1 = *(const float4*)(src + 4);
        v4u pk = {pk2bf(f0.x, f0.y), pk2bf(f0.z, f0.w),
                  pk2bf(f1.x, f1.y), pk2bf(f1.z, f1.w)};
        *(v4u*)&Wf[((size_t)(hk * 96 + wc)) * 64 + ((c ^ (wc & 7)) * 8)] = pk;
        return;
    }
    {                                           // wproj_t: 256 rows x 32 chunks
        int idx = (bid - 704) * 256 + tid;      // 0..8191
        int m = idx >> 5, ck = idx & 31;
        const float* src = Wproj + (size_t)m * 256 + ck * 8;
        int rt = m >> 7, rr = m & 127, kt = ck >> 3, c = ck & 7;
        float4 f0 = *(const float4*)src;
        float4 f1 = *(const float4*)(src + 4);
        v4u pk = {pk2bf(f0.x, f0.y), pk2bf(f0.z, f0.w),
                  pk2bf(f1.x, f1.y), pk2bf(f1.z, f1.w)};
        *(v4u*)&wproj_t[((size_t)(rt * 4 + kt) * 128 + rr) * 64 + ((c ^ (rr & 7)) * 8)] = pk;
    }
}

// ---------------- K23: fused QKV GEMM + attention (512 threads, 8 waves) ----------------
// block = (b,h) with id = h*64 + b  (8 h-blocks of one b share an XCD -> x[b] L2-local)
__global__ __launch_bounds__(512, 4) void fused_qkv_attn(
    const float* __restrict__ x, const ushort* __restrict__ Wf,
    const ushort* __restrict__ gpos, const float* __restrict__ gating,
    ushort* __restrict__ ot)
{
    __shared__ ushort smem[25600];     // 51200 B
    ushort* Xs = smem;                 // GEMM: [304][64] swizzled (38912 B)
    ushort* Wsh = smem + 19456;        // GEMM: [96][64] swizzled (12288 B)
    ushort* Ks = smem;                 // ATTN: [304][40] (24320 B)
    ushort* Vt = smem + 12160;         // ATTN: [32][328] (20992 B)

    int bid = blockIdx.x, b = bid & 63, h = bid >> 6;
    int tid = threadIdx.x, wave = tid >> 6, lane = tid & 63, li = lane & 15, qd = lane >> 4;

    const float* xb = x + (size_t)b * 300 * 256;
    const ushort* wfh = Wf + (size_t)h * 4 * 6144;

    v4f acc[3][6];
#pragma unroll
    for (int i = 0; i < 3; ++i)
#pragma unroll
        for (int j = 0; j < 6; ++j) acc[i][j] = (v4f){0.f, 0.f, 0.f, 0.f};

    // -------- GEMM phase: q|k|v[304x96] = X[304x256] @ W[256x96] --------
    // W: global_load_lds DMA (pre-swizzled). X: reg-staged from RAW fp32 x,
    // swizzle folded into global column selection, linear ds_write_b128.
    for (int kt = 0; kt < 4; ++kt) {
        // Ws: 768 DMA chunks of 16B
        gl_lds16(wfh + (size_t)kt * 6144 + tid * 8, Wsh + tid * 8);
        if (tid < 256)
            gl_lds16(wfh + (size_t)kt * 6144 + (512 + tid) * 8, Wsh + (512 + tid) * 8);
        // Xs: 2432 chunks of 16B (8 bf16), converted in-register
#pragma unroll
        for (int s = 0; s < 4; ++s) {
            int cch = s * 512 + tid;
            int r = cch >> 3, sl = cch & 7;
            int lc = sl ^ (r & 7);              // logical chunk held at slot sl
            v4u pk = {0u, 0u, 0u, 0u};
            if (r < 300) {
                const float* src = xb + (size_t)r * 256 + kt * 64 + lc * 8;
                float4 f0 = *(const float4*)src;
                float4 f1 = *(const float4*)(src + 4);
                pk = (v4u){cvtpk(f0.x, f0.y), cvtpk(f0.z, f0.w),
                           cvtpk(f1.x, f1.y), cvtpk(f1.z, f1.w)};
            }
            *(v4u*)&Xs[cch * 8] = pk;
        }
        if (tid < 384) {
            int cch = 2048 + tid;
            int r = cch >> 3, sl = cch & 7;
            int lc = sl ^ (r & 7);
            v4u pk = {0u, 0u, 0u, 0u};
            if (r < 300) {
                const float* src = xb + (size_t)r * 256 + kt * 64 + lc * 8;
                float4 f0 = *(const float4*)src;
                float4 f1 = *(const float4*)(src + 4);
                pk = (v4u){cvtpk(f0.x, f0.y), cvtpk(f0.z, f0.w),
                           cvtpk(f1.x, f1.y), cvtpk(f1.z, f1.w)};
            }
            *(v4u*)&Xs[cch * 8] = pk;
        }
        __syncthreads();                       // drains DMA + LDS writes
#pragma unroll
        for (int kc = 0; kc < 64; kc += 32) {
            int cb = (kc >> 3) + qd;
            int cs = cb ^ (li & 7);
            v8s bw[6];
#pragma unroll
            for (int ct = 0; ct < 6; ++ct)
                bw[ct] = *(const v8s*)&Wsh[(ct * 16 + li) * 64 + cs * 8];
#pragma unroll
            for (int i = 0; i < 3; ++i) {
                int rt = wave + i * 8;
                if (rt < 19) {
                    v8s ax = *(const v8s*)&Xs[(rt * 16 + li) * 64 + cs * 8];
#pragma unroll
                    for (int ct = 0; ct < 6; ++ct)
                        acc[i][ct] = __builtin_amdgcn_mfma_f32_16x16x32_bf16(bw[ct], ax, acc[i][ct], 0, 0, 0);
                }
            }
        }
        __syncthreads();
    }

    // -------- writeback: q -> registers (cross-qd shuffle), k/v -> LDS --------
    // swapped-operand acc: C[row = rt*16+li][col = ct*16 + qd*4 + r]
    const float QSC = 0.25503486063f;          // log2(e)/sqrt(32)
    v4u q0 = {0,0,0,0}, q1 = {0,0,0,0}, q2 = {0,0,0,0};
    int srcA = ((qd & 1) << 5) + li;           // lane of qd' = (qd&1)*2
    int srcB = srcA + 16;                      // lane of qd' = (qd&1)*2 + 1
#pragma unroll
    for (int i = 0; i < 3; ++i) {
        int rt = wave + i * 8;
        if (rt < 19) {                         // wave-uniform guard
            unsigned W00 = cvtpk(acc[i][0][0] * QSC, acc[i][0][1] * QSC);
            unsigned W01 = cvtpk(acc[i][0][2] * QSC, acc[i][0][3] * QSC);
            unsigned W10 = cvtpk(acc[i][1][0] * QSC, acc[i][1][1] * QSC);
            unsigned W11 = cvtpk(acc[i][1][2] * QSC, acc[i][1][3] * QSC);
            unsigned a0 = __shfl(W00, srcA), a1 = __shfl(W01, srcA);
            unsigned a2 = __shfl(W00, srcB), a3 = __shfl(W01, srcB);
            unsigned b0 = __shfl(W10, srcA), b1 = __shfl(W11, srcA);
            unsigned b2 = __shfl(W10, srcB), b3 = __shfl(W11, srcB);
            bool hi = (qd >= 2);
            v4u qq = {hi ? b0 : a0, hi ? b1 : a1, hi ? b2 : a2, hi ? b3 : a3};
            if (i == 0) q0 = qq; else if (i == 1) q1 = qq; else q2 = qq;

            int row = rt * 16 + li;
#pragma unroll
            for (int ct = 2; ct < 4; ++ct) {   // k -> Ks[row][dim]
                uint2 wk = {cvtpk(acc[i][ct][0], acc[i][ct][1]),
                            cvtpk(acc[i][ct][2], acc[i][ct][3])};
                *(uint2*)&Ks[row * 40 + (ct - 2) * 16 + qd * 4] = wk;
            }
#pragma unroll
            for (int ct = 4; ct < 6; ++ct)     // v -> Vt[dim][row] (transposed)
#pragma unroll
                for (int r = 0; r < 4; ++r)
                    Vt[((ct - 4) * 16 + qd * 4 + r) * 328 + row] = f2bf(acc[i][ct][r]);
        }
    }
    float g = 1.f / (1.f + __expf(-gating[h]));
    float omg = 1.f - g;
    __syncthreads();

    // -------- attention phase (pair-packed loop, 2-deep gpos prefetch) --------
    const ushort* ksp0 = &Ks[li * 40 + qd * 8];
    const ushort* vtp0 = &Vt[li * 328 + qd * 4];
    const ushort* vtp1 = &Vt[(16 + li) * 328 + qd * 4];
    const v4f z4 = {0.f, 0.f, 0.f, 0.f};

#pragma unroll 1
    for (int rg = wave; rg < 19; rg += 8) {
        int i0 = rg * 16;
        // Q rows >= 300 are exact zeros (zero-padded X) -> masked at store
        v8s bq = __builtin_bit_cast(v8s, q0);
        const ushort* gp = gpos + ((size_t)h * 304 + (i0 + li)) * 304 + qd * 4;

        v4f Oe0 = z4, Oe1 = z4, Og0 = z4, Og1 = z4;
        float esum = 0.f;

        // prologue: pair-0 K/V operands + scores; gpos pairs 0 and 1 in flight
        v8s ak0 = *(const v8s*)(ksp0);
        v8s ak1 = *(const v8s*)(ksp0 + 640);
        uint2 v0a = *(const uint2*)(vtp0);
        uint2 v0b = *(const uint2*)(vtp0 + 16);
        uint2 v1a = *(const uint2*)(vtp1);
        uint2 v1b = *(const uint2*)(vtp1 + 16);
        uint2 gc0 = *(const uint2*)(gp);            // pair 0 (tiles 0,1)
        uint2 gc1 = *(const uint2*)(gp + 16);
        uint2 gn0 = *(const uint2*)(gp + 32);       // pair 1 (tiles 2,3)
        uint2 gn1 = *(const uint2*)(gp + 48);
        v4f s0n = __builtin_amdgcn_mfma_f32_16x16x32_bf16(ak0, bq, z4, 0, 0, 0);
        v4f s1n = __builtin_amdgcn_mfma_f32_16x16x32_bf16(ak1, bq, z4, 0, 0, 0);

#pragma unroll 1
        for (int p = 0; p < 9; ++p) {          // pairs (nt=2p, 2p+1), nt<=17
            v4f s0 = s0n, s1 = s1n;
            v8s b0 = __builtin_bit_cast(v8s, (v4u){v0a.x, v0a.y, v0b.x, v0b.y});
            v8s b1 = __builtin_bit_cast(v8s, (v4u){v1a.x, v1a.y, v1b.x, v1b.y});
            v8s ag = __builtin_bit_cast(v8s, (v4u){gc0.x, gc0.y, gc1.x, gc1.y});
            gc0 = gn0; gc1 = gn1;              // shift gpos pipeline
            int nt0 = 2 * p + 2;               // next pair (p=8 -> tail tile 18)
            int nt1 = (p < 8) ? nt0 + 1 : 18;
            int gt0 = (p < 7) ? 2 * p + 4 : 18;  // pair p+2 (clamp to tail)
            int gt1 = (p < 7) ? 2 * p + 5 : 18;
            ak0 = *(const v8s*)(ksp0 + nt0 * 640);
            ak1 = *(const v8s*)(ksp0 + nt1 * 640);
            v0a = *(const uint2*)(vtp0 + nt0 * 16);
            v0b = *(const uint2*)(vtp0 + nt1 * 16);
            v1a = *(const uint2*)(vtp1 + nt0 * 16);
            v1b = *(const uint2*)(vtp1 + nt1 * 16);
            gn0 = *(const uint2*)(gp + gt0 * 16);
            gn1 = *(const uint2*)(gp + gt1 * 16);
            s0n = __builtin_amdgcn_mfma_f32_16x16x32_bf16(ak0, bq, z4, 0, 0, 0);
            s1n = __builtin_amdgcn_mfma_f32_16x16x32_bf16(ak1, bq, z4, 0, 0, 0);

            float e0 = fexp2(s0[0]);           // log2(e) folded into q scale
            float e1 = fexp2(s0[1]);
            float e2 = fexp2(s0[2]);
            float e3 = fexp2(s0[3]);
            float f0 = fexp2(s1[0]);
            float f1 = fexp2(s1[1]);
            float f2 = fexp2(s1[2]);
            float f3 = fexp2(s1[3]);
            esum += ((e0 + e1) + (e2 + e3)) + ((f0 + f1) + (f2 + f3));
            v8s ae = __builtin_bit_cast(v8s, (v4u){cvtpk(e0, e1), cvtpk(e2, e3),
                                                   cvtpk(f0, f1), cvtpk(f2, f3)});
            __builtin_amdgcn_s_setprio(1);
            Oe0 = __builtin_amdgcn_mfma_f32_16x16x32_bf16(ae, b0, Oe0, 0, 0, 0);
            Oe1 = __builtin_amdgcn_mfma_f32_16x16x32_bf16(ae, b1, Oe1, 0, 0, 0);
            Og0 = __builtin_amdgcn_mfma_f32_16x16x32_bf16(ag, b0, Og0, 0, 0, 0);
            Og1 = __builtin_amdgcn_mfma_f32_16x16x32_bf16(ag, b1, Og1, 0, 0, 0);
            __builtin_amdgcn_s_setprio(0);
        }
        {   // tail tile nt=18 (j=288..303): scores in s0n; gc0 holds tile 18
            float e0 = fexp2(s0n[0]);
            float e1 = fexp2(s0n[1]);
            float e2 = fexp2(s0n[2]);
            float e3 = fexp2(s0n[3]);
            if (qd == 3) { e0 = e1 = e2 = e3 = 0.f; }   // j >= 300
            esum += (e0 + e1) + (e2 + e3);
            v8s ae = __builtin_bit_cast(v8s, (v4u){cvtpk(e0, e1), cvtpk(e2, e3), 0u, 0u});
            v8s ag = __builtin_bit_cast(v8s, (v4u){gc0.x, gc0.y, 0u, 0u});
            v8s b0 = __builtin_bit_cast(v8s, (v4u){v0a.x, v0a.y, 0u, 0u});
            v8s b1 = __builtin_bit_cast(v8s, (v4u){v1a.x, v1a.y, 0u, 0u});
            Oe0 = __builtin_amdgcn_mfma_f32_16x16x32_bf16(ae, b0, Oe0, 0, 0, 0);
            Oe1 = __builtin_amdgcn_mfma_f32_16x16x32_bf16(ae, b1, Oe1, 0, 0, 0);
            Og0 = __builtin_amdgcn_mfma_f32_16x16x32_bf16(ag, b0, Og0, 0, 0, 0);
            Og1 = __builtin_amdgcn_mfma_f32_16x16x32_bf16(ag, b1, Og1, 0, 0, 0);
        }
        esum += __shfl_xor(esum, 16);
        esum += __shfl_xor(esum, 32);          // full row sum for query i0+li
        float ps = omg / esum;                 // (skip /attn.sum: it's 1 +- 1e-6)
        float psr[4];
#pragma unroll
        for (int r = 0; r < 4; ++r) psr[r] = __shfl(ps, qd * 4 + r);
#pragma unroll
        for (int r = 0; r < 4; ++r) {
            int row = i0 + qd * 4 + r;
            if (row < NSEQ) {
                int m = b * NSEQ + row;
                int rt = m >> 7, rr = m & 127;
                int c0 = (h & 1) * 4 + (li >> 3);
                int p2 = li & 7;
                size_t tb = ((size_t)(rt * 4 + (h >> 1)) * 128 + rr) * 64;
                ot[tb + ((c0 ^ (rr & 7)) * 8) + p2] = f2bf(fmaf(psr[r], Oe0[r], Og0[r]));
                ot[tb + (((c0 + 2) ^ (rr & 7)) * 8) + p2] = f2bf(fmaf(psr[r], Oe1[r], Og1[r]));
            }
        }
        q0 = q1; q1 = q2;                      // rotate q registers (static idx)
    }
}

// ---------------- K4: output projection, BM=64, DMA staging + bias ----------------
__global__ __launch_bounds__(256, 4) void gemm_proj_mfma(
    const ushort* __restrict__ A, const ushort* __restrict__ Bw,
    const float* __restrict__ bias, float* __restrict__ out)
{
    __shared__ ushort As[64 * 64];    // 8 KB
    __shared__ ushort Bs[128 * 64];   // 16 KB
    int tid = threadIdx.x;
    int wave = tid >> 6, lane = tid & 63, li = lane & 15, qd = lane >> 4;
    int rh = wave >> 1, ch = wave & 1;
    int by = blockIdx.y;
    const ushort* gA = A + ((size_t)(by >> 1) * 4 * 128 + (by & 1) * 64) * 64;
    const ushort* gB = Bw + (size_t)blockIdx.x * 4 * 8192;

    v4f acc[2][4];
#pragma unroll
    for (int i = 0; i < 2; ++i)
#pragma unroll
        for (int j = 0; j < 4; ++j) acc[i][j] = (v4f){0.f, 0.f, 0.f, 0.f};

    for (int kt = 0; kt < 4; ++kt) {
#pragma unroll
        for (int s = 0; s < 2; ++s) {
            int cch = s * 256 + tid;
            gl_lds16(gA + (size_t)kt * 128 * 64 + cch * 8, As + cch * 8);
        }
#pragma unroll
        for (int s = 0; s < 4; ++s) {
            int cch = s * 256 + tid;
            gl_lds16(gB + (size_t)kt * 8192 + cch * 8, Bs + cch * 8);
        }
        __syncthreads();
#pragma unroll
        for (int kc = 0; kc < 64; kc += 32) {
            int cb = (kc >> 3) + qd;
            int cs = cb ^ (li & 7);
            v8s a[2], b[4];
#pragma unroll
            for (int mt = 0; mt < 2; ++mt)
                a[mt] = *(const v8s*)&As[(rh * 32 + mt * 16 + li) * 64 + cs * 8];
#pragma unroll
            for (int nt = 0; nt < 4; ++nt)
                b[nt] = *(const v8s*)&Bs[(ch * 64 + nt * 16 + li) * 64 + cs * 8];
#pragma unroll
            for (int mt = 0; mt < 2; ++mt)
#pragma unroll
                for (int nt = 0; nt < 4; ++nt)
                    acc[mt][nt] = __builtin_amdgcn_mfma_f32_16x16x32_bf16(b[nt], a[mt], acc[mt][nt], 0, 0, 0);
        }
        __syncthreads();
    }

#pragma unroll
    for (int mt = 0; mt < 2; ++mt) {
        int row = by * 64 + rh * 32 + mt * 16 + li;
#pragma unroll
        for (int nt = 0; nt < 4; ++nt) {
            int col = blockIdx.x * 128 + ch * 64 + nt * 16 + qd * 4;
            float4 bv = *(const float4*)&bias[col];
            float4 st = {acc[mt][nt][0] + bv.x, acc[mt][nt][1] + bv.y,
                         acc[mt][nt][2] + bv.z, acc[mt][nt][3] + bv.w};
            *(float4*)&out[(size_t)row * 256 + col] = st;
        }
    }
}

extern "C" void kernel_launch(void* const* d_in, const int* in_sizes, int n_in,
                              void* d_out, int out_size, void* d_ws, size_t ws_size,
                              hipStream_t stream) {
    const float* x      = (const float*)d_in[0];
    const float* Wqk    = (const float*)d_in[1];
    const float* Wv     = (const float*)d_in[2];
    const float* Wpos   = (const float*)d_in[3];
    const float* bpos   = (const float*)d_in[4];
    const float* Wproj  = (const float*)d_in[5];
    const float* bproj  = (const float*)d_in[6];
    const float* gating = (const float*)d_in[7];
    float* out = (float*)d_out;

    ushort* gpos     = (ushort*)d_ws;             // 8*304*304 = 739,328
    ushort* Wf       = gpos + 739328;             // 8*4*96*64 = 196,608 (swizzled)
    ushort* wproj_t  = Wf + 196608;               // 65,536 (tiled+swizzled)
    ushort* o_t      = wproj_t + 65536;           // 4,915,200 (tiled+swizzled)

    prep_kernel<<<736, 256, 0, stream>>>(Wqk, Wv, Wproj, Wpos, bpos, gating,
                                         Wf, wproj_t, gpos);
    fused_qkv_attn<<<512, 512, 0, stream>>>(x, Wf, gpos, gating, o_t);
    gemm_proj_mfma<<<dim3(2, 300), 256, 0, stream>>>(o_t, wproj_t, bproj, out);
}

// Round 10
// 123.266 us; speedup vs baseline: 1.0302x; 1.0124x over previous
//
#include <hip/hip_runtime.h>

// GPSA bf16-MFMA v17. B=64, N=300, C=256, H=8, hd=32.
// v14 (best, 122.9us) with ONE change: proj re-tiled BN 128->64.
//   grid (2,300)=600 blocks @2.3/CU  ->  (4,300)=1200 blocks @4.7/CU.
//   Latency-bound small GEMM wants occupancy, not tile size. Bs 16->8KB,
//   acc[2][4]->[2][2]. Per-element K order unchanged -> bitwise identical.
// K0 prep: x->x_bf [64][304][256] + gpos softmax + Wf + wproj_t (v14 exact).
// K23 fused_qkv_attn: v14 exact (512 thr, Q-in-regs, DMA staging).

#define NSEQ 300
#define HEADS 8
#define HD 32

typedef short v8s __attribute__((ext_vector_type(8)));
typedef float v4f __attribute__((ext_vector_type(4)));
typedef unsigned int v4u __attribute__((ext_vector_type(4)));

__device__ __forceinline__ ushort f2bf(float f) {
    unsigned u = __float_as_uint(f);
    u = (u + 0x7FFFu + ((u >> 16) & 1u)) >> 16;   // RNE
    return (ushort)u;
}

// pack two fp32 -> packed bf16x2 (lo=a, hi=b) via v_perm
__device__ __forceinline__ unsigned pk2bf(float a, float b) {
    unsigned ua = __float_as_uint(a), ub = __float_as_uint(b);
    ua += 0x7FFFu + ((ua >> 16) & 1u);
    ub += 0x7FFFu + ((ub >> 16) & 1u);
    return __builtin_amdgcn_perm(ub, ua, 0x07060302);  // [ua.hi16 | ub.hi16]
}

// single-instruction RNE pack (lo=a, hi=b)
__device__ __forceinline__ unsigned cvtpk(float a, float b) {
    unsigned r;
    asm("v_cvt_pk_bf16_f32 %0, %1, %2" : "=v"(r) : "v"(a), "v"(b));
    return r;
}

__device__ __forceinline__ float fexp2(float x) {
    float r; asm("v_exp_f32 %0, %1" : "=v"(r) : "v"(x)); return r;
}

// async global->LDS DMA, 16B per lane
__device__ __forceinline__ void gl_lds16(const ushort* g, ushort* l) {
    __builtin_amdgcn_global_load_lds(
        (const __attribute__((address_space(1))) void*)g,
        (__attribute__((address_space(3))) void*)l, 16, 0, 0);
}

// ---------------- K0: prep = x->bf16 + gpos softmax + weight swizzle ----------------
// blocks 0..2431: x_bf | 2432..3039: gpos | 3040..3135: Wf | 3136..3167: wproj_t
__global__ __launch_bounds__(256) void prep_kernel(
    const float* __restrict__ x,
    const float* __restrict__ Wqk, const float* __restrict__ Wv,
    const float* __restrict__ Wproj, const float* __restrict__ Wpos,
    const float* __restrict__ bpos, const float* __restrict__ gating,
    ushort* __restrict__ x_bf, ushort* __restrict__ Wf,
    ushort* __restrict__ wproj_t, ushort* __restrict__ gpos)
{
    int bid = blockIdx.x, tid = threadIdx.x;
    if (bid < 2432) {                           // x -> x_bf [64][304][256], zero-pad
        int idx = bid * 256 + tid;              // 0..622591
        int c8 = idx & 31;
        int mrow = idx >> 5;                    // b*304 + r
        unsigned b = (unsigned)mrow / 304u;
        int r = mrow - (int)b * 304;
        v4u pk = {0u, 0u, 0u, 0u};
        if (r < 300) {
            const float* src = x + ((size_t)b * 300 + r) * 256 + c8 * 8;
            float4 f0 = *(const float4*)src;
            float4 f1 = *(const float4*)(src + 4);
            pk = (v4u){pk2bf(f0.x, f0.y), pk2bf(f0.z, f0.w),
                       pk2bf(f1.x, f1.y), pk2bf(f1.z, f1.w)};
        }
        *(v4u*)&x_bf[(size_t)mrow * 256 + c8 * 8] = pk;
        return;
    }
    if (bid < 3040) {                           // gated positional softmax
        int sub = bid - 2432;
        int h = sub / 76;
        int i = (sub % 76) * 4 + (tid >> 6);    // row 0..303
        int lane = tid & 63;
        ushort* gr = gpos + ((size_t)h * 304 + i) * 304;
        if (i >= NSEQ) {
#pragma unroll
            for (int t = 0; t < 5; ++t) {
                int j = lane + 64 * t;
                if (j < 304) gr[j] = 0;
            }
            return;
        }
        float w0 = Wpos[h * 3 + 0], w2 = Wpos[h * 3 + 2], bb = bpos[h];
        float g = 1.f / (1.f + __expf(-gating[h]));
        float sv[5]; float m2 = -1e30f;
#pragma unroll
        for (int t = 0; t < 5; ++t) {
            int j = lane + 64 * t;
            float d = (float)(j - i);
            float lg = fmaf(w2, d * d, fmaf(w0, d, bb));
            sv[t] = (j < NSEQ) ? lg : -1e30f;   // logits +-7000: max-sub required
            m2 = fmaxf(m2, sv[t]);
        }
#pragma unroll
        for (int off = 32; off > 0; off >>= 1) m2 = fmaxf(m2, __shfl_xor(m2, off));
        float sum = 0.f;
#pragma unroll
        for (int t = 0; t < 5; ++t) { sv[t] = __expf(sv[t] - m2); sum += sv[t]; }
#pragma unroll
        for (int off = 32; off > 0; off >>= 1) sum += __shfl_xor(sum, off);
        float gi = g / sum;
#pragma unroll
        for (int t = 0; t < 5; ++t) {
            int j = lane + 64 * t;
            if (j < NSEQ) gr[j] = f2bf(sv[t] * gi);
            else if (j < 304) gr[j] = 0;
        }
        return;
    }
    if (bid < 3136) {                           // Wf: 8h x 4kt x 96 rows x 8 chunks
        int idx = (bid - 3040) * 256 + tid;     // 0..24575
        int c = idx & 7;
        int t = idx >> 3;                       // 0..3071
        int hk = t / 96;                        // h*4+kt
        int wc = t - hk * 96;                   // 0..95
        int h = hk >> 2, kt = hk & 3;
        const float* src;
        if (wc < 32)      src = Wqk + (size_t)(h * 32 + wc) * 256;
        else if (wc < 64) src = Wqk + (size_t)(256 + h * 32 + (wc - 32)) * 256;
        else              src = Wv + (size_t)(h * 32 + (wc - 64)) * 256;
        src += kt * 64 + c * 8;
        float4 f0 = *(const float4*)src;
        float4 f1 = *(const float4*)(src + 4);
        v4u pk = {pk2bf(f0.x, f0.y), pk2bf(f0.z, f0.w),
                  pk2bf(f1.x, f1.y), pk2bf(f1.z, f1.w)};
        *(v4u*)&Wf[((size_t)(hk * 96 + wc)) * 64 + ((c ^ (wc & 7)) * 8)] = pk;
        return;
    }
    {                                           // wproj_t: 256 rows x 32 chunks
        int idx = (bid - 3136) * 256 + tid;     // 0..8191
        int m = idx >> 5, ck = idx & 31;
        const float* src = Wproj + (size_t)m * 256 + ck * 8;
        int rt = m >> 7, rr = m & 127, kt = ck >> 3, c = ck & 7;
        float4 f0 = *(const float4*)src;
        float4 f1 = *(const float4*)(src + 4);
        v4u pk = {pk2bf(f0.x, f0.y), pk2bf(f0.z, f0.w),
                  pk2bf(f1.x, f1.y), pk2bf(f1.z, f1.w)};
        *(v4u*)&wproj_t[((size_t)(rt * 4 + kt) * 128 + rr) * 64 + ((c ^ (rr & 7)) * 8)] = pk;
    }
}

// ---------------- K23: fused QKV GEMM + attention (512 threads, 8 waves) ----------------
// block = (b,h) with id = h*64 + b  (8 h-blocks of one b share an XCD)
__global__ __launch_bounds__(512, 4) void fused_qkv_attn(
    const ushort* __restrict__ x_bf, const ushort* __restrict__ Wf,
    const ushort* __restrict__ gpos, const float* __restrict__ gating,
    ushort* __restrict__ ot)
{
    __shared__ ushort smem[25600];     // 51200 B
    ushort* Xs = smem;                 // GEMM: [304][64] swizzled (38912 B)
    ushort* Wsh = smem + 19456;        // GEMM: [96][64] swizzled (12288 B)
    ushort* Ks = smem;                 // ATTN: [304][40] (24320 B)
    ushort* Vt = smem + 12160;         // ATTN: [32][328] (20992 B)

    int bid = blockIdx.x, b = bid & 63, h = bid >> 6;
    int tid = threadIdx.x, wave = tid >> 6, lane = tid & 63, li = lane & 15, qd = lane >> 4;

    const ushort* xbb = x_bf + (size_t)b * 304 * 256;
    const ushort* wfh = Wf + (size_t)h * 4 * 6144;

    v4f acc[3][6];
#pragma unroll
    for (int i = 0; i < 3; ++i)
#pragma unroll
        for (int j = 0; j < 6; ++j) acc[i][j] = (v4f){0.f, 0.f, 0.f, 0.f};

    // -------- GEMM phase: q|k|v[304x96] = X[304x256] @ W[256x96] --------
    for (int kt = 0; kt < 4; ++kt) {
        // Ws: 768 DMA chunks of 16B
        gl_lds16(wfh + (size_t)kt * 6144 + tid * 8, Wsh + tid * 8);
        if (tid < 256)
            gl_lds16(wfh + (size_t)kt * 6144 + (512 + tid) * 8, Wsh + (512 + tid) * 8);
        // Xs: 2432 chunks
#pragma unroll
        for (int s = 0; s < 4; ++s) {
            int cch = s * 512 + tid;
            int r = cch >> 3, sl = cch & 7;
            gl_lds16(xbb + (size_t)r * 256 + kt * 64 + ((sl ^ (r & 7)) * 8),
                     Xs + cch * 8);
        }
        if (tid < 384) {
            int cch = 2048 + tid;
            int r = cch >> 3, sl = cch & 7;
            gl_lds16(xbb + (size_t)r * 256 + kt * 64 + ((sl ^ (r & 7)) * 8),
                     Xs + cch * 8);
        }
        __syncthreads();                       // drains vmcnt (DMA)
#pragma unroll
        for (int kc = 0; kc < 64; kc += 32) {
            int cb = (kc >> 3) + qd;
            int cs = cb ^ (li & 7);
            v8s bw[6];
#pragma unroll
            for (int ct = 0; ct < 6; ++ct)
                bw[ct] = *(const v8s*)&Wsh[(ct * 16 + li) * 64 + cs * 8];
#pragma unroll
            for (int i = 0; i < 3; ++i) {
                int rt = wave + i * 8;
                if (rt < 19) {
                    v8s ax = *(const v8s*)&Xs[(rt * 16 + li) * 64 + cs * 8];
#pragma unroll
                    for (int ct = 0; ct < 6; ++ct)
                        acc[i][ct] = __builtin_amdgcn_mfma_f32_16x16x32_bf16(bw[ct], ax, acc[i][ct], 0, 0, 0);
                }
            }
        }
        __syncthreads();
    }

    // -------- writeback: q -> registers (cross-qd shuffle), k/v -> LDS --------
    // swapped-operand acc: C[row = rt*16+li][col = ct*16 + qd*4 + r]
    const float QSC = 0.25503486063f;          // log2(e)/sqrt(32)
    v4u q0 = {0,0,0,0}, q1 = {0,0,0,0}, q2 = {0,0,0,0};
    int srcA = ((qd & 1) << 5) + li;           // lane of qd' = (qd&1)*2
    int srcB = srcA + 16;                      // lane of qd' = (qd&1)*2 + 1
#pragma unroll
    for (int i = 0; i < 3; ++i) {
        int rt = wave + i * 8;
        if (rt < 19) {                         // wave-uniform guard
            unsigned W00 = cvtpk(acc[i][0][0] * QSC, acc[i][0][1] * QSC);
            unsigned W01 = cvtpk(acc[i][0][2] * QSC, acc[i][0][3] * QSC);
            unsigned W10 = cvtpk(acc[i][1][0] * QSC, acc[i][1][1] * QSC);
            unsigned W11 = cvtpk(acc[i][1][2] * QSC, acc[i][1][3] * QSC);
            unsigned a0 = __shfl(W00, srcA), a1 = __shfl(W01, srcA);
            unsigned a2 = __shfl(W00, srcB), a3 = __shfl(W01, srcB);
            unsigned b0 = __shfl(W10, srcA), b1 = __shfl(W11, srcA);
            unsigned b2 = __shfl(W10, srcB), b3 = __shfl(W11, srcB);
            bool hi = (qd >= 2);
            v4u qq = {hi ? b0 : a0, hi ? b1 : a1, hi ? b2 : a2, hi ? b3 : a3};
            if (i == 0) q0 = qq; else if (i == 1) q1 = qq; else q2 = qq;

            int row = rt * 16 + li;
#pragma unroll
            for (int ct = 2; ct < 4; ++ct) {   // k -> Ks[row][dim]
                uint2 wk = {cvtpk(acc[i][ct][0], acc[i][ct][1]),
                            cvtpk(acc[i][ct][2], acc[i][ct][3])};
                *(uint2*)&Ks[row * 40 + (ct - 2) * 16 + qd * 4] = wk;
            }
#pragma unroll
            for (int ct = 4; ct < 6; ++ct)     // v -> Vt[dim][row] (transposed)
#pragma unroll
                for (int r = 0; r < 4; ++r)
                    Vt[((ct - 4) * 16 + qd * 4 + r) * 328 + row] = f2bf(acc[i][ct][r]);
        }
    }
    float g = 1.f / (1.f + __expf(-gating[h]));
    float omg = 1.f - g;
    __syncthreads();

    // -------- attention phase (pair-packed loop, 2-deep gpos prefetch) --------
    const ushort* ksp0 = &Ks[li * 40 + qd * 8];
    const ushort* vtp0 = &Vt[li * 328 + qd * 4];
    const ushort* vtp1 = &Vt[(16 + li) * 328 + qd * 4];
    const v4f z4 = {0.f, 0.f, 0.f, 0.f};

#pragma unroll 1
    for (int rg = wave; rg < 19; rg += 8) {
        int i0 = rg * 16;
        // Q rows >= 300 are exact zeros (zero-padded X) -> masked at store
        v8s bq = __builtin_bit_cast(v8s, q0);
        const ushort* gp = gpos + ((size_t)h * 304 + (i0 + li)) * 304 + qd * 4;

        v4f Oe0 = z4, Oe1 = z4, Og0 = z4, Og1 = z4;
        float esum = 0.f;

        // prologue: pair-0 K/V operands + scores; gpos pairs 0 and 1 in flight
        v8s ak0 = *(const v8s*)(ksp0);
        v8s ak1 = *(const v8s*)(ksp0 + 640);
        uint2 v0a = *(const uint2*)(vtp0);
        uint2 v0b = *(const uint2*)(vtp0 + 16);
        uint2 v1a = *(const uint2*)(vtp1);
        uint2 v1b = *(const uint2*)(vtp1 + 16);
        uint2 gc0 = *(const uint2*)(gp);            // pair 0 (tiles 0,1)
        uint2 gc1 = *(const uint2*)(gp + 16);
        uint2 gn0 = *(const uint2*)(gp + 32);       // pair 1 (tiles 2,3)
        uint2 gn1 = *(const uint2*)(gp + 48);
        v4f s0n = __builtin_amdgcn_mfma_f32_16x16x32_bf16(ak0, bq, z4, 0, 0, 0);
        v4f s1n = __builtin_amdgcn_mfma_f32_16x16x32_bf16(ak1, bq, z4, 0, 0, 0);

#pragma unroll 1
        for (int p = 0; p < 9; ++p) {          // pairs (nt=2p, 2p+1), nt<=17
            v4f s0 = s0n, s1 = s1n;
            v8s b0 = __builtin_bit_cast(v8s, (v4u){v0a.x, v0a.y, v0b.x, v0b.y});
            v8s b1 = __builtin_bit_cast(v8s, (v4u){v1a.x, v1a.y, v1b.x, v1b.y});
            v8s ag = __builtin_bit_cast(v8s, (v4u){gc0.x, gc0.y, gc1.x, gc1.y});
            gc0 = gn0; gc1 = gn1;              // shift gpos pipeline
            int nt0 = 2 * p + 2;               // next pair (p=8 -> tail tile 18)
            int nt1 = (p < 8) ? nt0 + 1 : 18;
            int gt0 = (p < 7) ? 2 * p + 4 : 18;  // pair p+2 (clamp to tail)
            int gt1 = (p < 7) ? 2 * p + 5 : 18;
            ak0 = *(const v8s*)(ksp0 + nt0 * 640);
            ak1 = *(const v8s*)(ksp0 + nt1 * 640);
            v0a = *(const uint2*)(vtp0 + nt0 * 16);
            v0b = *(const uint2*)(vtp0 + nt1 * 16);
            v1a = *(const uint2*)(vtp1 + nt0 * 16);
            v1b = *(const uint2*)(vtp1 + nt1 * 16);
            gn0 = *(const uint2*)(gp + gt0 * 16);
            gn1 = *(const uint2*)(gp + gt1 * 16);
            s0n = __builtin_amdgcn_mfma_f32_16x16x32_bf16(ak0, bq, z4, 0, 0, 0);
            s1n = __builtin_amdgcn_mfma_f32_16x16x32_bf16(ak1, bq, z4, 0, 0, 0);

            float e0 = fexp2(s0[0]);           // log2(e) folded into q scale
            float e1 = fexp2(s0[1]);
            float e2 = fexp2(s0[2]);
            float e3 = fexp2(s0[3]);
            float f0 = fexp2(s1[0]);
            float f1 = fexp2(s1[1]);
            float f2 = fexp2(s1[2]);
            float f3 = fexp2(s1[3]);
            esum += ((e0 + e1) + (e2 + e3)) + ((f0 + f1) + (f2 + f3));
            v8s ae = __builtin_bit_cast(v8s, (v4u){cvtpk(e0, e1), cvtpk(e2, e3),
                                                   cvtpk(f0, f1), cvtpk(f2, f3)});
            __builtin_amdgcn_s_setprio(1);
            Oe0 = __builtin_amdgcn_mfma_f32_16x16x32_bf16(ae, b0, Oe0, 0, 0, 0);
            Oe1 = __builtin_amdgcn_mfma_f32_16x16x32_bf16(ae, b1, Oe1, 0, 0, 0);
            Og0 = __builtin_amdgcn_mfma_f32_16x16x32_bf16(ag, b0, Og0, 0, 0, 0);
            Og1 = __builtin_amdgcn_mfma_f32_16x16x32_bf16(ag, b1, Og1, 0, 0, 0);
            __builtin_amdgcn_s_setprio(0);
        }
        {   // tail tile nt=18 (j=288..303): scores in s0n; gc0 holds tile 18
            float e0 = fexp2(s0n[0]);
            float e1 = fexp2(s0n[1]);
            float e2 = fexp2(s0n[2]);
            float e3 = fexp2(s0n[3]);
            if (qd == 3) { e0 = e1 = e2 = e3 = 0.f; }   // j >= 300
            esum += (e0 + e1) + (e2 + e3);
            v8s ae = __builtin_bit_cast(v8s, (v4u){cvtpk(e0, e1), cvtpk(e2, e3), 0u, 0u});
            v8s ag = __builtin_bit_cast(v8s, (v4u){gc0.x, gc0.y, 0u, 0u});
            v8s b0 = __builtin_bit_cast(v8s, (v4u){v0a.x, v0a.y, 0u, 0u});
            v8s b1 = __builtin_bit_cast(v8s, (v4u){v1a.x, v1a.y, 0u, 0u});
            Oe0 = __builtin_amdgcn_mfma_f32_16x16x32_bf16(ae, b0, Oe0, 0, 0, 0);
            Oe1 = __builtin_amdgcn_mfma_f32_16x16x32_bf16(ae, b1, Oe1, 0, 0, 0);
            Og0 = __builtin_amdgcn_mfma_f32_16x16x32_bf16(ag, b0, Og0, 0, 0, 0);
            Og1 = __builtin_amdgcn_mfma_f32_16x16x32_bf16(ag, b1, Og1, 0, 0, 0);
        }
        esum += __shfl_xor(esum, 16);
        esum += __shfl_xor(esum, 32);          // full row sum for query i0+li
        float ps = omg / esum;                 // (skip /attn.sum: it's 1 +- 1e-6)
        float psr[4];
#pragma unroll
        for (int r = 0; r < 4; ++r) psr[r] = __shfl(ps, qd * 4 + r);
#pragma unroll
        for (int r = 0; r < 4; ++r) {
            int row = i0 + qd * 4 + r;
            if (row < NSEQ) {
                int m = b * NSEQ + row;
                int rt = m >> 7, rr = m & 127;
                int c0 = (h & 1) * 4 + (li >> 3);
                int p2 = li & 7;
                size_t tb = ((size_t)(rt * 4 + (h >> 1)) * 128 + rr) * 64;
                ot[tb + ((c0 ^ (rr & 7)) * 8) + p2] = f2bf(fmaf(psr[r], Oe0[r], Og0[r]));
                ot[tb + (((c0 + 2) ^ (rr & 7)) * 8) + p2] = f2bf(fmaf(psr[r], Oe1[r], Og1[r]));
            }
        }
        q0 = q1; q1 = q2;                      // rotate q registers (static idx)
    }
}

// ---------------- K4: output projection, BM=64 BN=64, 1200 blocks ----------------
__global__ __launch_bounds__(256, 4) void gemm_proj_mfma(
    const ushort* __restrict__ A, const ushort* __restrict__ Bw,
    const float* __restrict__ bias, float* __restrict__ out)
{
    __shared__ ushort As[64 * 64];    // 8 KB
    __shared__ ushort Bs[64 * 64];    // 8 KB
    int tid = threadIdx.x;
    int wave = tid >> 6, lane = tid & 63, li = lane & 15, qd = lane >> 4;
    int rh = wave >> 1, ch = wave & 1;  // wave: 32 rows x 32 cols quadrant
    int by = blockIdx.y, bx = blockIdx.x;
    const ushort* gA = A + ((size_t)(by >> 1) * 4 * 128 + (by & 1) * 64) * 64;
    const ushort* gB = Bw + ((size_t)(bx >> 1) * 4 * 128 + (bx & 1) * 64) * 64;

    v4f acc[2][2];
#pragma unroll
    for (int i = 0; i < 2; ++i)
#pragma unroll
        for (int j = 0; j < 2; ++j) acc[i][j] = (v4f){0.f, 0.f, 0.f, 0.f};

    for (int kt = 0; kt < 4; ++kt) {
#pragma unroll
        for (int s = 0; s < 2; ++s) {
            int cch = s * 256 + tid;          // 512 chunks each
            gl_lds16(gA + (size_t)kt * 8192 + cch * 8, As + cch * 8);
            gl_lds16(gB + (size_t)kt * 8192 + cch * 8, Bs + cch * 8);
        }
        __syncthreads();
#pragma unroll
        for (int kc = 0; kc < 64; kc += 32) {
            int cb = (kc >> 3) + qd;
            int cs = cb ^ (li & 7);
            v8s a[2], b[2];
#pragma unroll
            for (int mt = 0; mt < 2; ++mt)
                a[mt] = *(const v8s*)&As[(rh * 32 + mt * 16 + li) * 64 + cs * 8];
#pragma unroll
            for (int nt = 0; nt < 2; ++nt)
                b[nt] = *(const v8s*)&Bs[(ch * 32 + nt * 16 + li) * 64 + cs * 8];
#pragma unroll
            for (int mt = 0; mt < 2; ++mt)
#pragma unroll
                for (int nt = 0; nt < 2; ++nt)
                    acc[mt][nt] = __builtin_amdgcn_mfma_f32_16x16x32_bf16(b[nt], a[mt], acc[mt][nt], 0, 0, 0);
        }
        __syncthreads();
    }

#pragma unroll
    for (int mt = 0; mt < 2; ++mt) {
        int row = by * 64 + rh * 32 + mt * 16 + li;
#pragma unroll
        for (int nt = 0; nt < 2; ++nt) {
            int col = bx * 64 + ch * 32 + nt * 16 + qd * 4;
            float4 bv = *(const float4*)&bias[col];
            float4 st = {acc[mt][nt][0] + bv.x, acc[mt][nt][1] + bv.y,
                         acc[mt][nt][2] + bv.z, acc[mt][nt][3] + bv.w};
            *(float4*)&out[(size_t)row * 256 + col] = st;
        }
    }
}

extern "C" void kernel_launch(void* const* d_in, const int* in_sizes, int n_in,
                              void* d_out, int out_size, void* d_ws, size_t ws_size,
                              hipStream_t stream) {
    const float* x      = (const float*)d_in[0];
    const float* Wqk    = (const float*)d_in[1];
    const float* Wv     = (const float*)d_in[2];
    const float* Wpos   = (const float*)d_in[3];
    const float* bpos   = (const float*)d_in[4];
    const float* Wproj  = (const float*)d_in[5];
    const float* bproj  = (const float*)d_in[6];
    const float* gating = (const float*)d_in[7];
    float* out = (float*)d_out;

    ushort* gpos     = (ushort*)d_ws;             // 8*304*304 = 739,328
    ushort* Wf       = gpos + 739328;             // 8*4*96*64 = 196,608 (swizzled)
    ushort* wproj_t  = Wf + 196608;               // 65,536 (tiled+swizzled)
    ushort* o_t      = wproj_t + 65536;           // 4,915,200 (tiled+swizzled)
    ushort* x_bf     = o_t + 4915200;             // 64*304*256 = 4,980,736

    prep_kernel<<<3168, 256, 0, stream>>>(x, Wqk, Wv, Wproj, Wpos, bpos, gating,
                                          x_bf, Wf, wproj_t, gpos);
    fused_qkv_attn<<<512, 512, 0, stream>>>(x_bf, Wf, gpos, gating, o_t);
    gemm_proj_mfma<<<dim3(4, 300), 256, 0, stream>>>(o_t, wproj_t, bproj, out);
}

// Round 11
// 121.663 us; speedup vs baseline: 1.0437x; 1.0132x over previous
//
#include <hip/hip_runtime.h>

// GPSA bf16-MFMA v18. B=64, N=300, C=256, H=8, hd=32.
// v14 base (best, 122.9us) + attention-loop ISSUE-count reduction:
//  - Vt pair-interleaved [32][328]: slot p*32+qd*8+t*4+j = V[d][(2p+t)*16+qd*4+j]
//    -> PV B-operands are ONE ds_read_b128 each (was 2x b64 + 4 movs).
//    Tile-19 slots zeroed -> tail's zero-hi operand comes free from pair-9 read.
//  - gpos2 pair-interleaved [h][304][320]: ONE global dwordx4 per pair yields
//    the ag operand directly (was 2x b64 + movs); j>=300 slots auto-zero.
//  - Affine pair loop 0..8 (all-real tiles), prefetched pair 9 feeds the tail;
//    per-iter cndmask index chains removed.
// Numerics bit-identical to v14 (same values, same accumulation order).
// K0 prep: x->x_bf + gpos2 (permuted layout) + Wf + wproj_t.
// K4 proj: v14 exact (BM64xBN128, grid (2,300)).

#define NSEQ 300
#define HEADS 8
#define HD 32

typedef short v8s __attribute__((ext_vector_type(8)));
typedef float v4f __attribute__((ext_vector_type(4)));
typedef unsigned int v4u __attribute__((ext_vector_type(4)));

__device__ __forceinline__ ushort f2bf(float f) {
    unsigned u = __float_as_uint(f);
    u = (u + 0x7FFFu + ((u >> 16) & 1u)) >> 16;   // RNE
    return (ushort)u;
}

// pack two fp32 -> packed bf16x2 (lo=a, hi=b) via v_perm
__device__ __forceinline__ unsigned pk2bf(float a, float b) {
    unsigned ua = __float_as_uint(a), ub = __float_as_uint(b);
    ua += 0x7FFFu + ((ua >> 16) & 1u);
    ub += 0x7FFFu + ((ub >> 16) & 1u);
    return __builtin_amdgcn_perm(ub, ua, 0x07060302);  // [ua.hi16 | ub.hi16]
}

// single-instruction RNE pack (lo=a, hi=b)
__device__ __forceinline__ unsigned cvtpk(float a, float b) {
    unsigned r;
    asm("v_cvt_pk_bf16_f32 %0, %1, %2" : "=v"(r) : "v"(a), "v"(b));
    return r;
}

__device__ __forceinline__ float fexp2(float x) {
    float r; asm("v_exp_f32 %0, %1" : "=v"(r) : "v"(x)); return r;
}

// async global->LDS DMA, 16B per lane
__device__ __forceinline__ void gl_lds16(const ushort* g, ushort* l) {
    __builtin_amdgcn_global_load_lds(
        (const __attribute__((address_space(1))) void*)g,
        (__attribute__((address_space(3))) void*)l, 16, 0, 0);
}

// ---------------- K0: prep = x->bf16 + gpos2 softmax + weight swizzle ----------------
// blocks 0..2431: x_bf | 2432..3039: gpos2 | 3040..3135: Wf | 3136..3167: wproj_t
__global__ __launch_bounds__(256) void prep_kernel(
    const float* __restrict__ x,
    const float* __restrict__ Wqk, const float* __restrict__ Wv,
    const float* __restrict__ Wproj, const float* __restrict__ Wpos,
    const float* __restrict__ bpos, const float* __restrict__ gating,
    ushort* __restrict__ x_bf, ushort* __restrict__ Wf,
    ushort* __restrict__ wproj_t, ushort* __restrict__ gpos)
{
    int bid = blockIdx.x, tid = threadIdx.x;
    if (bid < 2432) {                           // x -> x_bf [64][304][256], zero-pad
        int idx = bid * 256 + tid;              // 0..622591
        int c8 = idx & 31;
        int mrow = idx >> 5;                    // b*304 + r
        unsigned b = (unsigned)mrow / 304u;
        int r = mrow - (int)b * 304;
        v4u pk = {0u, 0u, 0u, 0u};
        if (r < 300) {
            const float* src = x + ((size_t)b * 300 + r) * 256 + c8 * 8;
            float4 f0 = *(const float4*)src;
            float4 f1 = *(const float4*)(src + 4);
            pk = (v4u){pk2bf(f0.x, f0.y), pk2bf(f0.z, f0.w),
                       pk2bf(f1.x, f1.y), pk2bf(f1.z, f1.w)};
        }
        *(v4u*)&x_bf[(size_t)mrow * 256 + c8 * 8] = pk;
        return;
    }
    if (bid < 3040) {                           // gpos2: pair-interleaved rows [320]
        int sub = bid - 2432;
        int h = sub / 76;
        int i = (sub % 76) * 4 + (tid >> 6);    // row 0..303
        int lane = tid & 63;
        ushort* gr = gpos + ((size_t)h * 304 + i) * 320;
        if (i >= NSEQ) {
#pragma unroll
            for (int t = 0; t < 5; ++t) gr[lane + 64 * t] = 0;
            return;
        }
        float w0 = Wpos[h * 3 + 0], w2 = Wpos[h * 3 + 2], bb = bpos[h];
        float g = 1.f / (1.f + __expf(-gating[h]));
        float sv[5]; int jj[5]; float m2 = -1e30f;
#pragma unroll
        for (int t = 0; t < 5; ++t) {
            int pos = lane + 64 * t;            // slot p*32 + qd*8 + tt*4 + e4
            int p = pos >> 5, rem = pos & 31;
            int qd = rem >> 3, r8 = rem & 7;
            int nt = 2 * p + (r8 >> 2);
            int j = nt * 16 + qd * 4 + (r8 & 3);
            jj[t] = j;
            float d = (float)(j - i);
            float lg = fmaf(w2, d * d, fmaf(w0, d, bb));
            sv[t] = (j < NSEQ) ? lg : -1e30f;   // logits +-7000: max-sub required
            m2 = fmaxf(m2, sv[t]);
        }
#pragma unroll
        for (int off = 32; off > 0; off >>= 1) m2 = fmaxf(m2, __shfl_xor(m2, off));
        float sum = 0.f;
#pragma unroll
        for (int t = 0; t < 5; ++t) { sv[t] = __expf(sv[t] - m2); sum += sv[t]; }
#pragma unroll
        for (int off = 32; off > 0; off >>= 1) sum += __shfl_xor(sum, off);
        float gi = g / sum;
#pragma unroll
        for (int t = 0; t < 5; ++t)
            gr[lane + 64 * t] = (jj[t] < NSEQ) ? f2bf(sv[t] * gi) : 0;
        return;
    }
    if (bid < 3136) {                           // Wf: 8h x 4kt x 96 rows x 8 chunks
        int idx = (bid - 3040) * 256 + tid;     // 0..24575
        int c = idx & 7;
        int t = idx >> 3;                       // 0..3071
        int hk = t / 96;                        // h*4+kt
        int wc = t - hk * 96;                   // 0..95
        int h = hk >> 2, kt = hk & 3;
        const float* src;
        if (wc < 32)      src = Wqk + (size_t)(h * 32 + wc) * 256;
        else if (wc < 64) src = Wqk + (size_t)(256 + h * 32 + (wc - 32)) * 256;
        else              src = Wv + (size_t)(h * 32 + (wc - 64)) * 256;
        src += kt * 64 + c * 8;
        float4 f0 = *(const float4*)src;
        float4 f1 = *(const float4*)(src + 4);
        v4u pk = {pk2bf(f0.x, f0.y), pk2bf(f0.z, f0.w),
                  pk2bf(f1.x, f1.y), pk2bf(f1.z, f1.w)};
        *(v4u*)&Wf[((size_t)(hk * 96 + wc)) * 64 + ((c ^ (wc & 7)) * 8)] = pk;
        return;
    }
    {                                           // wproj_t: 256 rows x 32 chunks
        int idx = (bid - 3136) * 256 + tid;     // 0..8191
        int m = idx >> 5, ck = idx & 31;
        const float* src = Wproj + (size_t)m * 256 + ck * 8;
        int rt = m >> 7, rr = m & 127, kt = ck >> 3, c = ck & 7;
        float4 f0 = *(const float4*)src;
        float4 f1 = *(const float4*)(src + 4);
        v4u pk = {pk2bf(f0.x, f0.y), pk2bf(f0.z, f0.w),
                  pk2bf(f1.x, f1.y), pk2bf(f1.z, f1.w)};
        *(v4u*)&wproj_t[((size_t)(rt * 4 + kt) * 128 + rr) * 64 + ((c ^ (rr & 7)) * 8)] = pk;
    }
}

// ---------------- K23: fused QKV GEMM + attention (512 threads, 8 waves) ----------------
// block = (b,h) with id = h*64 + b  (8 h-blocks of one b share an XCD)
__global__ __launch_bounds__(512, 4) void fused_qkv_attn(
    const ushort* __restrict__ x_bf, const ushort* __restrict__ Wf,
    const ushort* __restrict__ gpos, const float* __restrict__ gating,
    ushort* __restrict__ ot)
{
    __shared__ ushort smem[25600];     // 51200 B
    ushort* Xs = smem;                 // GEMM: [304][64] swizzled (38912 B)
    ushort* Wsh = smem + 19456;        // GEMM: [96][64] swizzled (12288 B)
    ushort* Ks = smem;                 // ATTN: [304][40] (24320 B)
    ushort* Vt = smem + 12160;         // ATTN: [32][328] pair-interleaved

    int bid = blockIdx.x, b = bid & 63, h = bid >> 6;
    int tid = threadIdx.x, wave = tid >> 6, lane = tid & 63, li = lane & 15, qd = lane >> 4;

    const ushort* xbb = x_bf + (size_t)b * 304 * 256;
    const ushort* wfh = Wf + (size_t)h * 4 * 6144;

    v4f acc[3][6];
#pragma unroll
    for (int i = 0; i < 3; ++i)
#pragma unroll
        for (int j = 0; j < 6; ++j) acc[i][j] = (v4f){0.f, 0.f, 0.f, 0.f};

    // -------- GEMM phase: q|k|v[304x96] = X[304x256] @ W[256x96] --------
    for (int kt = 0; kt < 4; ++kt) {
        // Ws: 768 DMA chunks of 16B
        gl_lds16(wfh + (size_t)kt * 6144 + tid * 8, Wsh + tid * 8);
        if (tid < 256)
            gl_lds16(wfh + (size_t)kt * 6144 + (512 + tid) * 8, Wsh + (512 + tid) * 8);
        // Xs: 2432 chunks
#pragma unroll
        for (int s = 0; s < 4; ++s) {
            int cch = s * 512 + tid;
            int r = cch >> 3, sl = cch & 7;
            gl_lds16(xbb + (size_t)r * 256 + kt * 64 + ((sl ^ (r & 7)) * 8),
                     Xs + cch * 8);
        }
        if (tid < 384) {
            int cch = 2048 + tid;
            int r = cch >> 3, sl = cch & 7;
            gl_lds16(xbb + (size_t)r * 256 + kt * 64 + ((sl ^ (r & 7)) * 8),
                     Xs + cch * 8);
        }
        __syncthreads();                       // drains vmcnt (DMA)
#pragma unroll
        for (int kc = 0; kc < 64; kc += 32) {
            int cb = (kc >> 3) + qd;
            int cs = cb ^ (li & 7);
            v8s bw[6];
#pragma unroll
            for (int ct = 0; ct < 6; ++ct)
                bw[ct] = *(const v8s*)&Wsh[(ct * 16 + li) * 64 + cs * 8];
#pragma unroll
            for (int i = 0; i < 3; ++i) {
                int rt = wave + i * 8;
                if (rt < 19) {
                    v8s ax = *(const v8s*)&Xs[(rt * 16 + li) * 64 + cs * 8];
#pragma unroll
                    for (int ct = 0; ct < 6; ++ct)
                        acc[i][ct] = __builtin_amdgcn_mfma_f32_16x16x32_bf16(bw[ct], ax, acc[i][ct], 0, 0, 0);
                }
            }
        }
        __syncthreads();
    }

    // -------- writeback: q -> registers (cross-qd shuffle), k/v -> LDS --------
    // swapped-operand acc: C[row = rt*16+li][col = ct*16 + qd*4 + r]
    const float QSC = 0.25503486063f;          // log2(e)/sqrt(32)
    v4u q0 = {0,0,0,0}, q1 = {0,0,0,0}, q2 = {0,0,0,0};
    int srcA = ((qd & 1) << 5) + li;           // lane of qd' = (qd&1)*2
    int srcB = srcA + 16;                      // lane of qd' = (qd&1)*2 + 1
    {   // zero-fill Vt tile-19 slots (pair 9, t=1): d = tid>>4, slot from tid&15
        int d = tid >> 4, s = tid & 15;
        Vt[d * 328 + 288 + (s >> 2) * 8 + 4 + (s & 3)] = 0;
    }
#pragma unroll
    for (int i = 0; i < 3; ++i) {
        int rt = wave + i * 8;
        if (rt < 19) {                         // wave-uniform guard
            unsigned W00 = cvtpk(acc[i][0][0] * QSC, acc[i][0][1] * QSC);
            unsigned W01 = cvtpk(acc[i][0][2] * QSC, acc[i][0][3] * QSC);
            unsigned W10 = cvtpk(acc[i][1][0] * QSC, acc[i][1][1] * QSC);
            unsigned W11 = cvtpk(acc[i][1][2] * QSC, acc[i][1][3] * QSC);
            unsigned a0 = __shfl(W00, srcA), a1 = __shfl(W01, srcA);
            unsigned a2 = __shfl(W00, srcB), a3 = __shfl(W01, srcB);
            unsigned b0 = __shfl(W10, srcA), b1 = __shfl(W11, srcA);
            unsigned b2 = __shfl(W10, srcB), b3 = __shfl(W11, srcB);
            bool hi = (qd >= 2);
            v4u qq = {hi ? b0 : a0, hi ? b1 : a1, hi ? b2 : a2, hi ? b3 : a3};
            if (i == 0) q0 = qq; else if (i == 1) q1 = qq; else q2 = qq;

            int row = rt * 16 + li;
#pragma unroll
            for (int ct = 2; ct < 4; ++ct) {   // k -> Ks[row][dim]
                uint2 wk = {cvtpk(acc[i][ct][0], acc[i][ct][1]),
                            cvtpk(acc[i][ct][2], acc[i][ct][3])};
                *(uint2*)&Ks[row * 40 + (ct - 2) * 16 + qd * 4] = wk;
            }
            // v -> Vt pair-interleaved: row rt*16+li -> p=rt>>1, t=rt&1,
            // slot = p*32 + (li>>2)*8 + t*4 + (li&3)
            int vt_off = (rt >> 1) * 32 + ((li >> 2) * 8) + ((rt & 1) * 4) + (li & 3);
#pragma unroll
            for (int ct = 4; ct < 6; ++ct)
#pragma unroll
                for (int r = 0; r < 4; ++r)
                    Vt[((ct - 4) * 16 + qd * 4 + r) * 328 + vt_off] = f2bf(acc[i][ct][r]);
        }
    }
    float g = 1.f / (1.f + __expf(-gating[h]));
    float omg = 1.f - g;
    __syncthreads();

    // -------- attention phase (pair-packed, 1-load-per-operand) --------
    const ushort* ksp0 = &Ks[li * 40 + qd * 8];
    const ushort* vtb0 = &Vt[li * 328 + qd * 8];
    const ushort* vtb1 = &Vt[(16 + li) * 328 + qd * 8];
    const v4f z4 = {0.f, 0.f, 0.f, 0.f};

#pragma unroll 1
    for (int rg = wave; rg < 19; rg += 8) {
        int i0 = rg * 16;
        // Q rows >= 300 are exact zeros (zero-padded X) -> masked at store
        v8s bq = __builtin_bit_cast(v8s, q0);
        const ushort* gp = gpos + ((size_t)h * 304 + (i0 + li)) * 320 + qd * 8;

        v4f Oe0 = z4, Oe1 = z4, Og0 = z4, Og1 = z4;
        float esum = 0.f;

        // prologue: pair-0 operands + scores; gpos pairs 0,1 in flight
        v8s ak0 = *(const v8s*)(ksp0);            // tile 0
        v8s ak1 = *(const v8s*)(ksp0 + 640);      // tile 1
        v8s vb0c = *(const v8s*)(vtb0);           // V pair 0, dims li
        v8s vb1c = *(const v8s*)(vtb1);           // V pair 0, dims li+16
        v8s agc = *(const v8s*)(gp);              // gpos pair 0
        v8s agn = *(const v8s*)(gp + 32);         // gpos pair 1
        v4f s0n = __builtin_amdgcn_mfma_f32_16x16x32_bf16(ak0, bq, z4, 0, 0, 0);
        v4f s1n = __builtin_amdgcn_mfma_f32_16x16x32_bf16(ak1, bq, z4, 0, 0, 0);

#pragma unroll 1
        for (int p = 0; p < 9; ++p) {          // pairs 0..8 (tiles 0..17, all real)
            v4f s0 = s0n, s1 = s1n;
            v8s b0 = vb0c, b1 = vb1c, ag = agc;
            agc = agn;
            int gt = (p < 7) ? p + 2 : 9;      // clamp gpos prefetch to pair 9
            ak0 = *(const v8s*)(ksp0 + (2 * p + 2) * 640);
            ak1 = *(const v8s*)(ksp0 + (2 * p + 3) * 640);  // p=8: finite garbage, discarded
            vb0c = *(const v8s*)(vtb0 + (p + 1) * 32);
            vb1c = *(const v8s*)(vtb1 + (p + 1) * 32);
            agn = *(const v8s*)(gp + gt * 32);
            s0n = __builtin_amdgcn_mfma_f32_16x16x32_bf16(ak0, bq, z4, 0, 0, 0);
            s1n = __builtin_amdgcn_mfma_f32_16x16x32_bf16(ak1, bq, z4, 0, 0, 0);

            float e0 = fexp2(s0[0]);           // log2(e) folded into q scale
            float e1 = fexp2(s0[1]);
            float e2 = fexp2(s0[2]);
            float e3 = fexp2(s0[3]);
            float f0 = fexp2(s1[0]);
            float f1 = fexp2(s1[1]);
            float f2 = fexp2(s1[2]);
            float f3 = fexp2(s1[3]);
            esum += ((e0 + e1) + (e2 + e3)) + ((f0 + f1) + (f2 + f3));
            v8s ae = __builtin_bit_cast(v8s, (v4u){cvtpk(e0, e1), cvtpk(e2, e3),
                                                   cvtpk(f0, f1), cvtpk(f2, f3)});
            __builtin_amdgcn_s_setprio(1);
            Oe0 = __builtin_amdgcn_mfma_f32_16x16x32_bf16(ae, b0, Oe0, 0, 0, 0);
            Oe1 = __builtin_amdgcn_mfma_f32_16x16x32_bf16(ae, b1, Oe1, 0, 0, 0);
            Og0 = __builtin_amdgcn_mfma_f32_16x16x32_bf16(ag, b0, Og0, 0, 0, 0);
            Og1 = __builtin_amdgcn_mfma_f32_16x16x32_bf16(ag, b1, Og1, 0, 0, 0);
            __builtin_amdgcn_s_setprio(0);
        }
        {   // tail pair 9: tile 18 real, tile 19 slots are zeros (Vt/gpos2)
            float e0 = fexp2(s0n[0]);
            float e1 = fexp2(s0n[1]);
            float e2 = fexp2(s0n[2]);
            float e3 = fexp2(s0n[3]);
            if (qd == 3) { e0 = e1 = e2 = e3 = 0.f; }   // j >= 300
            esum += (e0 + e1) + (e2 + e3);
            v8s ae = __builtin_bit_cast(v8s, (v4u){cvtpk(e0, e1), cvtpk(e2, e3), 0u, 0u});
            Oe0 = __builtin_amdgcn_mfma_f32_16x16x32_bf16(ae, vb0c, Oe0, 0, 0, 0);
            Oe1 = __builtin_amdgcn_mfma_f32_16x16x32_bf16(ae, vb1c, Oe1, 0, 0, 0);
            Og0 = __builtin_amdgcn_mfma_f32_16x16x32_bf16(agc, vb0c, Og0, 0, 0, 0);
            Og1 = __builtin_amdgcn_mfma_f32_16x16x32_bf16(agc, vb1c, Og1, 0, 0, 0);
        }
        esum += __shfl_xor(esum, 16);
        esum += __shfl_xor(esum, 32);          // full row sum for query i0+li
        float ps = omg / esum;                 // (skip /attn.sum: it's 1 +- 1e-6)
        float psr[4];
#pragma unroll
        for (int r = 0; r < 4; ++r) psr[r] = __shfl(ps, qd * 4 + r);
#pragma unroll
        for (int r = 0; r < 4; ++r) {
            int row = i0 + qd * 4 + r;
            if (row < NSEQ) {
                int m = b * NSEQ + row;
                int rt = m >> 7, rr = m & 127;
                int c0 = (h & 1) * 4 + (li >> 3);
                int p2 = li & 7;
                size_t tb = ((size_t)(rt * 4 + (h >> 1)) * 128 + rr) * 64;
                ot[tb + ((c0 ^ (rr & 7)) * 8) + p2] = f2bf(fmaf(psr[r], Oe0[r], Og0[r]));
                ot[tb + (((c0 + 2) ^ (rr & 7)) * 8) + p2] = f2bf(fmaf(psr[r], Oe1[r], Og1[r]));
            }
        }
        q0 = q1; q1 = q2;                      // rotate q registers (static idx)
    }
}

// ---------------- K4: output projection, BM=64, DMA staging + bias ----------------
__global__ __launch_bounds__(256, 4) void gemm_proj_mfma(
    const ushort* __restrict__ A, const ushort* __restrict__ Bw,
    const float* __restrict__ bias, float* __restrict__ out)
{
    __shared__ ushort As[64 * 64];    // 8 KB
    __shared__ ushort Bs[128 * 64];   // 16 KB
    int tid = threadIdx.x;
    int wave = tid >> 6, lane = tid & 63, li = lane & 15, qd = lane >> 4;
    int rh = wave >> 1, ch = wave & 1;
    int by = blockIdx.y;
    const ushort* gA = A + ((size_t)(by >> 1) * 4 * 128 + (by & 1) * 64) * 64;
    const ushort* gB = Bw + (size_t)blockIdx.x * 4 * 8192;

    v4f acc[2][4];
#pragma unroll
    for (int i = 0; i < 2; ++i)
#pragma unroll
        for (int j = 0; j < 4; ++j) acc[i][j] = (v4f){0.f, 0.f, 0.f, 0.f};

    for (int kt = 0; kt < 4; ++kt) {
#pragma unroll
        for (int s = 0; s < 2; ++s) {
            int cch = s * 256 + tid;
            gl_lds16(gA + (size_t)kt * 128 * 64 + cch * 8, As + cch * 8);
        }
#pragma unroll
        for (int s = 0; s < 4; ++s) {
            int cch = s * 256 + tid;
            gl_lds16(gB + (size_t)kt * 8192 + cch * 8, Bs + cch * 8);
        }
        __syncthreads();
#pragma unroll
        for (int kc = 0; kc < 64; kc += 32) {
            int cb = (kc >> 3) + qd;
            int cs = cb ^ (li & 7);
            v8s a[2], b[4];
#pragma unroll
            for (int mt = 0; mt < 2; ++mt)
                a[mt] = *(const v8s*)&As[(rh * 32 + mt * 16 + li) * 64 + cs * 8];
#pragma unroll
            for (int nt = 0; nt < 4; ++nt)
                b[nt] = *(const v8s*)&Bs[(ch * 64 + nt * 16 + li) * 64 + cs * 8];
#pragma unroll
            for (int mt = 0; mt < 2; ++mt)
#pragma unroll
                for (int nt = 0; nt < 4; ++nt)
                    acc[mt][nt] = __builtin_amdgcn_mfma_f32_16x16x32_bf16(b[nt], a[mt], acc[mt][nt], 0, 0, 0);
        }
        __syncthreads();
    }

#pragma unroll
    for (int mt = 0; mt < 2; ++mt) {
        int row = by * 64 + rh * 32 + mt * 16 + li;
#pragma unroll
        for (int nt = 0; nt < 4; ++nt) {
            int col = blockIdx.x * 128 + ch * 64 + nt * 16 + qd * 4;
            float4 bv = *(const float4*)&bias[col];
            float4 st = {acc[mt][nt][0] + bv.x, acc[mt][nt][1] + bv.y,
                         acc[mt][nt][2] + bv.z, acc[mt][nt][3] + bv.w};
            *(float4*)&out[(size_t)row * 256 + col] = st;
        }
    }
}

extern "C" void kernel_launch(void* const* d_in, const int* in_sizes, int n_in,
                              void* d_out, int out_size, void* d_ws, size_t ws_size,
                              hipStream_t stream) {
    const float* x      = (const float*)d_in[0];
    const float* Wqk    = (const float*)d_in[1];
    const float* Wv     = (const float*)d_in[2];
    const float* Wpos   = (const float*)d_in[3];
    const float* bpos   = (const float*)d_in[4];
    const float* Wproj  = (const float*)d_in[5];
    const float* bproj  = (const float*)d_in[6];
    const float* gating = (const float*)d_in[7];
    float* out = (float*)d_out;

    ushort* gpos     = (ushort*)d_ws;             // 8*304*320 = 778,240 (pair-interleaved)
    ushort* Wf       = gpos + 778240;             // 8*4*96*64 = 196,608 (swizzled)
    ushort* wproj_t  = Wf + 196608;               // 65,536 (tiled+swizzled)
    ushort* o_t      = wproj_t + 65536;           // 4,915,200 (tiled+swizzled)
    ushort* x_bf     = o_t + 4915200;             // 64*304*256 = 4,980,736

    prep_kernel<<<3168, 256, 0, stream>>>(x, Wqk, Wv, Wproj, Wpos, bpos, gating,
                                          x_bf, Wf, wproj_t, gpos);
    fused_qkv_attn<<<512, 512, 0, stream>>>(x_bf, Wf, gpos, gating, o_t);
    gemm_proj_mfma<<<dim3(2, 300), 256, 0, stream>>>(o_t, wproj_t, bproj, out);
}

// Round 12
// 121.128 us; speedup vs baseline: 1.0484x; 1.0044x over previous
//
#include <hip/hip_runtime.h>

// GPSA bf16-MFMA v19. B=64, N=300, C=256, H=8, hd=32.
// v18 base (best, 121.7us) + BARRIER-SAFE double-buffered staging in both
// GEMM phases: issue(st+1) BEFORE compute(st), one __syncthreads per step.
// The barrier at step st+1 drains DMA that ran CONCURRENTLY with compute(st)
// -> overlap without inline-asm vmcnt (the idiom that failed containers).
//  - fused GEMM: BK=32, 8 steps; Xb 2x[304][32] + Wb 2x[96][32] = same
//    51200B LDS footprint; Wf re-laid [h][st][96][32] pre-swizzled.
//  - proj: BK=64 double-buffer (48KB, 3 blocks/CU), same reorder.
//  - K-slice order per accumulator unchanged -> bitwise-identical output.
// Attention phase/writeback/gpos2: v18 verbatim.

#define NSEQ 300
#define HEADS 8
#define HD 32

typedef short v8s __attribute__((ext_vector_type(8)));
typedef float v4f __attribute__((ext_vector_type(4)));
typedef unsigned int v4u __attribute__((ext_vector_type(4)));

__device__ __forceinline__ ushort f2bf(float f) {
    unsigned u = __float_as_uint(f);
    u = (u + 0x7FFFu + ((u >> 16) & 1u)) >> 16;   // RNE
    return (ushort)u;
}

// pack two fp32 -> packed bf16x2 (lo=a, hi=b) via v_perm
__device__ __forceinline__ unsigned pk2bf(float a, float b) {
    unsigned ua = __float_as_uint(a), ub = __float_as_uint(b);
    ua += 0x7FFFu + ((ua >> 16) & 1u);
    ub += 0x7FFFu + ((ub >> 16) & 1u);
    return __builtin_amdgcn_perm(ub, ua, 0x07060302);  // [ua.hi16 | ub.hi16]
}

// single-instruction RNE pack (lo=a, hi=b)
__device__ __forceinline__ unsigned cvtpk(float a, float b) {
    unsigned r;
    asm("v_cvt_pk_bf16_f32 %0, %1, %2" : "=v"(r) : "v"(a), "v"(b));
    return r;
}

__device__ __forceinline__ float fexp2(float x) {
    float r; asm("v_exp_f32 %0, %1" : "=v"(r) : "v"(x)); return r;
}

// async global->LDS DMA, 16B per lane
__device__ __forceinline__ void gl_lds16(const ushort* g, ushort* l) {
    __builtin_amdgcn_global_load_lds(
        (const __attribute__((address_space(1))) void*)g,
        (__attribute__((address_space(3))) void*)l, 16, 0, 0);
}

// ---------------- K0: prep = x->bf16 + gpos2 softmax + weight swizzle ----------------
// blocks 0..2431: x_bf | 2432..3039: gpos2 | 3040..3135: Wf | 3136..3167: wproj_t
__global__ __launch_bounds__(256) void prep_kernel(
    const float* __restrict__ x,
    const float* __restrict__ Wqk, const float* __restrict__ Wv,
    const float* __restrict__ Wproj, const float* __restrict__ Wpos,
    const float* __restrict__ bpos, const float* __restrict__ gating,
    ushort* __restrict__ x_bf, ushort* __restrict__ Wf,
    ushort* __restrict__ wproj_t, ushort* __restrict__ gpos)
{
    int bid = blockIdx.x, tid = threadIdx.x;
    if (bid < 2432) {                           // x -> x_bf [64][304][256], zero-pad
        int idx = bid * 256 + tid;              // 0..622591
        int c8 = idx & 31;
        int mrow = idx >> 5;                    // b*304 + r
        unsigned b = (unsigned)mrow / 304u;
        int r = mrow - (int)b * 304;
        v4u pk = {0u, 0u, 0u, 0u};
        if (r < 300) {
            const float* src = x + ((size_t)b * 300 + r) * 256 + c8 * 8;
            float4 f0 = *(const float4*)src;
            float4 f1 = *(const float4*)(src + 4);
            pk = (v4u){pk2bf(f0.x, f0.y), pk2bf(f0.z, f0.w),
                       pk2bf(f1.x, f1.y), pk2bf(f1.z, f1.w)};
        }
        *(v4u*)&x_bf[(size_t)mrow * 256 + c8 * 8] = pk;
        return;
    }
    if (bid < 3040) {                           // gpos2: pair-interleaved rows [320]
        int sub = bid - 2432;
        int h = sub / 76;
        int i = (sub % 76) * 4 + (tid >> 6);    // row 0..303
        int lane = tid & 63;
        ushort* gr = gpos + ((size_t)h * 304 + i) * 320;
        if (i >= NSEQ) {
#pragma unroll
            for (int t = 0; t < 5; ++t) gr[lane + 64 * t] = 0;
            return;
        }
        float w0 = Wpos[h * 3 + 0], w2 = Wpos[h * 3 + 2], bb = bpos[h];
        float g = 1.f / (1.f + __expf(-gating[h]));
        float sv[5]; int jj[5]; float m2 = -1e30f;
#pragma unroll
        for (int t = 0; t < 5; ++t) {
            int pos = lane + 64 * t;            // slot p*32 + qd*8 + tt*4 + e4
            int p = pos >> 5, rem = pos & 31;
            int qd = rem >> 3, r8 = rem & 7;
            int nt = 2 * p + (r8 >> 2);
            int j = nt * 16 + qd * 4 + (r8 & 3);
            jj[t] = j;
            float d = (float)(j - i);
            float lg = fmaf(w2, d * d, fmaf(w0, d, bb));
            sv[t] = (j < NSEQ) ? lg : -1e30f;   // logits +-7000: max-sub required
            m2 = fmaxf(m2, sv[t]);
        }
#pragma unroll
        for (int off = 32; off > 0; off >>= 1) m2 = fmaxf(m2, __shfl_xor(m2, off));
        float sum = 0.f;
#pragma unroll
        for (int t = 0; t < 5; ++t) { sv[t] = __expf(sv[t] - m2); sum += sv[t]; }
#pragma unroll
        for (int off = 32; off > 0; off >>= 1) sum += __shfl_xor(sum, off);
        float gi = g / sum;
#pragma unroll
        for (int t = 0; t < 5; ++t)
            gr[lane + 64 * t] = (jj[t] < NSEQ) ? f2bf(sv[t] * gi) : 0;
        return;
    }
    if (bid < 3136) {                           // Wf: [h][st][96][32], 4-chunk swizzle
        int idx = (bid - 3040) * 256 + tid;     // 0..24575
        int s = idx & 3;                        // LDS slot within row
        int t = idx >> 2;                       // 0..6143
        int hst = t / 96;                       // h*8+st
        int wc = t - hst * 96;                  // 0..95
        int st = hst & 7, h = hst >> 3;
        int lc = s ^ (wc & 3);                  // logical chunk held at slot s
        const float* src;
        if (wc < 32)      src = Wqk + (size_t)(h * 32 + wc) * 256;
        else if (wc < 64) src = Wqk + (size_t)(256 + h * 32 + (wc - 32)) * 256;
        else              src = Wv + (size_t)(h * 32 + (wc - 64)) * 256;
        src += st * 32 + lc * 8;
        float4 f0 = *(const float4*)src;
        float4 f1 = *(const float4*)(src + 4);
        v4u pk = {pk2bf(f0.x, f0.y), pk2bf(f0.z, f0.w),
                  pk2bf(f1.x, f1.y), pk2bf(f1.z, f1.w)};
        *(v4u*)&Wf[((size_t)(hst * 96 + wc)) * 32 + s * 8] = pk;
        return;
    }
    {                                           // wproj_t: 256 rows x 32 chunks
        int idx = (bid - 3136) * 256 + tid;     // 0..8191
        int m = idx >> 5, ck = idx & 31;
        const float* src = Wproj + (size_t)m * 256 + ck * 8;
        int rt = m >> 7, rr = m & 127, kt = ck >> 3, c = ck & 7;
        float4 f0 = *(const float4*)src;
        float4 f1 = *(const float4*)(src + 4);
        v4u pk = {pk2bf(f0.x, f0.y), pk2bf(f0.z, f0.w),
                  pk2bf(f1.x, f1.y), pk2bf(f1.z, f1.w)};
        *(v4u*)&wproj_t[((size_t)(rt * 4 + kt) * 128 + rr) * 64 + ((c ^ (rr & 7)) * 8)] = pk;
    }
}

// ---------------- K23: fused QKV GEMM + attention (512 threads, 8 waves) ----------------
// block = (b,h) with id = h*64 + b  (8 h-blocks of one b share an XCD)
__global__ __launch_bounds__(512, 4) void fused_qkv_attn(
    const ushort* __restrict__ x_bf, const ushort* __restrict__ Wf,
    const ushort* __restrict__ gpos, const float* __restrict__ gating,
    ushort* __restrict__ ot)
{
    __shared__ ushort smem[25600];     // 51200 B
    // GEMM overlay: Xb0 @0 (9728 us), Xb1 @9728, Wb0 @19456 (3072), Wb1 @22528
    // ATTN overlay: Ks [304][40] @0, Vt [32][328] @12160 (pair-interleaved)
    ushort* Ks = smem;
    ushort* Vt = smem + 12160;

    int bid = blockIdx.x, b = bid & 63, h = bid >> 6;
    int tid = threadIdx.x, wave = tid >> 6, lane = tid & 63, li = lane & 15, qd = lane >> 4;

    const ushort* xbb = x_bf + (size_t)b * 304 * 256;
    const ushort* wfh = Wf + (size_t)h * 24576;

    v4f acc[3][6];
#pragma unroll
    for (int i = 0; i < 3; ++i)
#pragma unroll
        for (int j = 0; j < 6; ++j) acc[i][j] = (v4f){0.f, 0.f, 0.f, 0.f};

    // -------- GEMM phase: q|k|v[304x96] = X[304x256] @ W[256x96] --------
    // BK=32, 8 steps, double-buffered; DMA for step st+1 issued BEFORE
    // compute(st) -> overlaps with compute; next barrier drains the rest.
    {
        ushort* Xb0 = smem;            ushort* Xb1 = smem + 9728;
        ushort* Wb0 = smem + 19456;    ushort* Wb1 = smem + 22528;

        auto issue_step = [&](int st, ushort* xb, ushort* wb) {
#pragma unroll
            for (int s = 0; s < 2; ++s) {
                int cch = s * 512 + tid;        // 0..1023 of 1216 X chunks
                int r = cch >> 2, sl = cch & 3;
                gl_lds16(xbb + (size_t)r * 256 + st * 32 + ((sl ^ (r & 3)) * 8),
                         xb + cch * 8);
            }
            if (tid < 192) {                    // X chunks 1024..1215
                int cch = 1024 + tid;
                int r = cch >> 2, sl = cch & 3;
                gl_lds16(xbb + (size_t)r * 256 + st * 32 + ((sl ^ (r & 3)) * 8),
                         xb + cch * 8);
            }
            if (tid < 384)                      // W: 384 chunks (pre-swizzled)
                gl_lds16(wfh + st * 3072 + tid * 8, wb + tid * 8);
        };

        issue_step(0, Xb0, Wb0);
#pragma unroll
        for (int st = 0; st < 8; ++st) {
            __syncthreads();                   // drains DMA for buf[st&1]
            if (st < 7)
                issue_step(st + 1, (st & 1) ? Xb0 : Xb1, (st & 1) ? Wb0 : Wb1);
            const ushort* xb = (st & 1) ? Xb1 : Xb0;
            const ushort* wb = (st & 1) ? Wb1 : Wb0;
            int cs = qd ^ (li & 3);
            v8s bw[6];
#pragma unroll
            for (int ct = 0; ct < 6; ++ct)
                bw[ct] = *(const v8s*)&wb[(ct * 16 + li) * 32 + cs * 8];
#pragma unroll
            for (int i = 0; i < 3; ++i) {
                int rt = wave + i * 8;
                if (rt < 19) {
                    v8s ax = *(const v8s*)&xb[(rt * 16 + li) * 32 + cs * 8];
#pragma unroll
                    for (int ct = 0; ct < 6; ++ct)
                        acc[i][ct] = __builtin_amdgcn_mfma_f32_16x16x32_bf16(bw[ct], ax, acc[i][ct], 0, 0, 0);
                }
            }
        }
        __syncthreads();                       // all compute done before overlay
    }

    // -------- writeback: q -> registers (cross-qd shuffle), k/v -> LDS --------
    // swapped-operand acc: C[row = rt*16+li][col = ct*16 + qd*4 + r]
    const float QSC = 0.25503486063f;          // log2(e)/sqrt(32)
    v4u q0 = {0,0,0,0}, q1 = {0,0,0,0}, q2 = {0,0,0,0};
    int srcA = ((qd & 1) << 5) + li;           // lane of qd' = (qd&1)*2
    int srcB = srcA + 16;                      // lane of qd' = (qd&1)*2 + 1
    {   // zero-fill Vt tile-19 slots (pair 9, t=1)
        int d = tid >> 4, s = tid & 15;
        Vt[d * 328 + 288 + (s >> 2) * 8 + 4 + (s & 3)] = 0;
    }
#pragma unroll
    for (int i = 0; i < 3; ++i) {
        int rt = wave + i * 8;
        if (rt < 19) {                         // wave-uniform guard
            unsigned W00 = cvtpk(acc[i][0][0] * QSC, acc[i][0][1] * QSC);
            unsigned W01 = cvtpk(acc[i][0][2] * QSC, acc[i][0][3] * QSC);
            unsigned W10 = cvtpk(acc[i][1][0] * QSC, acc[i][1][1] * QSC);
            unsigned W11 = cvtpk(acc[i][1][2] * QSC, acc[i][1][3] * QSC);
            unsigned a0 = __shfl(W00, srcA), a1 = __shfl(W01, srcA);
            unsigned a2 = __shfl(W00, srcB), a3 = __shfl(W01, srcB);
            unsigned b0 = __shfl(W10, srcA), b1 = __shfl(W11, srcA);
            unsigned b2 = __shfl(W10, srcB), b3 = __shfl(W11, srcB);
            bool hi = (qd >= 2);
            v4u qq = {hi ? b0 : a0, hi ? b1 : a1, hi ? b2 : a2, hi ? b3 : a3};
            if (i == 0) q0 = qq; else if (i == 1) q1 = qq; else q2 = qq;

            int row = rt * 16 + li;
#pragma unroll
            for (int ct = 2; ct < 4; ++ct) {   // k -> Ks[row][dim]
                uint2 wk = {cvtpk(acc[i][ct][0], acc[i][ct][1]),
                            cvtpk(acc[i][ct][2], acc[i][ct][3])};
                *(uint2*)&Ks[row * 40 + (ct - 2) * 16 + qd * 4] = wk;
            }
            // v -> Vt pair-interleaved: row rt*16+li -> p=rt>>1, t=rt&1,
            // slot = p*32 + (li>>2)*8 + t*4 + (li&3)
            int vt_off = (rt >> 1) * 32 + ((li >> 2) * 8) + ((rt & 1) * 4) + (li & 3);
#pragma unroll
            for (int ct = 4; ct < 6; ++ct)
#pragma unroll
                for (int r = 0; r < 4; ++r)
                    Vt[((ct - 4) * 16 + qd * 4 + r) * 328 + vt_off] = f2bf(acc[i][ct][r]);
        }
    }
    float g = 1.f / (1.f + __expf(-gating[h]));
    float omg = 1.f - g;
    __syncthreads();

    // -------- attention phase (pair-packed, 1-load-per-operand) --------
    const ushort* ksp0 = &Ks[li * 40 + qd * 8];
    const ushort* vtb0 = &Vt[li * 328 + qd * 8];
    const ushort* vtb1 = &Vt[(16 + li) * 328 + qd * 8];
    const v4f z4 = {0.f, 0.f, 0.f, 0.f};

#pragma unroll 1
    for (int rg = wave; rg < 19; rg += 8) {
        int i0 = rg * 16;
        // Q rows >= 300 are exact zeros (zero-padded X) -> masked at store
        v8s bq = __builtin_bit_cast(v8s, q0);
        const ushort* gp = gpos + ((size_t)h * 304 + (i0 + li)) * 320 + qd * 8;

        v4f Oe0 = z4, Oe1 = z4, Og0 = z4, Og1 = z4;
        float esum = 0.f;

        // prologue: pair-0 operands + scores; gpos pairs 0,1 in flight
        v8s ak0 = *(const v8s*)(ksp0);            // tile 0
        v8s ak1 = *(const v8s*)(ksp0 + 640);      // tile 1
        v8s vb0c = *(const v8s*)(vtb0);           // V pair 0, dims li
        v8s vb1c = *(const v8s*)(vtb1);           // V pair 0, dims li+16
        v8s agc = *(const v8s*)(gp);              // gpos pair 0
        v8s agn = *(const v8s*)(gp + 32);         // gpos pair 1
        v4f s0n = __builtin_amdgcn_mfma_f32_16x16x32_bf16(ak0, bq, z4, 0, 0, 0);
        v4f s1n = __builtin_amdgcn_mfma_f32_16x16x32_bf16(ak1, bq, z4, 0, 0, 0);

#pragma unroll 1
        for (int p = 0; p < 9; ++p) {          // pairs 0..8 (tiles 0..17, all real)
            v4f s0 = s0n, s1 = s1n;
            v8s b0 = vb0c, b1 = vb1c, ag = agc;
            agc = agn;
            int gt = (p < 7) ? p + 2 : 9;      // clamp gpos prefetch to pair 9
            ak0 = *(const v8s*)(ksp0 + (2 * p + 2) * 640);
            ak1 = *(const v8s*)(ksp0 + (2 * p + 3) * 640);  // p=8: finite garbage, discarded
            vb0c = *(const v8s*)(vtb0 + (p + 1) * 32);
            vb1c = *(const v8s*)(vtb1 + (p + 1) * 32);
            agn = *(const v8s*)(gp + gt * 32);
            s0n = __builtin_amdgcn_mfma_f32_16x16x32_bf16(ak0, bq, z4, 0, 0, 0);
            s1n = __builtin_amdgcn_mfma_f32_16x16x32_bf16(ak1, bq, z4, 0, 0, 0);

            float e0 = fexp2(s0[0]);           // log2(e) folded into q scale
            float e1 = fexp2(s0[1]);
            float e2 = fexp2(s0[2]);
            float e3 = fexp2(s0[3]);
            float f0 = fexp2(s1[0]);
            float f1 = fexp2(s1[1]);
            float f2 = fexp2(s1[2]);
            float f3 = fexp2(s1[3]);
            esum += ((e0 + e1) + (e2 + e3)) + ((f0 + f1) + (f2 + f3));
            v8s ae = __builtin_bit_cast(v8s, (v4u){cvtpk(e0, e1), cvtpk(e2, e3),
                                                   cvtpk(f0, f1), cvtpk(f2, f3)});
            __builtin_amdgcn_s_setprio(1);
            Oe0 = __builtin_amdgcn_mfma_f32_16x16x32_bf16(ae, b0, Oe0, 0, 0, 0);
            Oe1 = __builtin_amdgcn_mfma_f32_16x16x32_bf16(ae, b1, Oe1, 0, 0, 0);
            Og0 = __builtin_amdgcn_mfma_f32_16x16x32_bf16(ag, b0, Og0, 0, 0, 0);
            Og1 = __builtin_amdgcn_mfma_f32_16x16x32_bf16(ag, b1, Og1, 0, 0, 0);
            __builtin_amdgcn_s_setprio(0);
        }
        {   // tail pair 9: tile 18 real, tile 19 slots are zeros (Vt/gpos2)
            float e0 = fexp2(s0n[0]);
            float e1 = fexp2(s0n[1]);
            float e2 = fexp2(s0n[2]);
            float e3 = fexp2(s0n[3]);
            if (qd == 3) { e0 = e1 = e2 = e3 = 0.f; }   // j >= 300
            esum += (e0 + e1) + (e2 + e3);
            v8s ae = __builtin_bit_cast(v8s, (v4u){cvtpk(e0, e1), cvtpk(e2, e3), 0u, 0u});
            Oe0 = __builtin_amdgcn_mfma_f32_16x16x32_bf16(ae, vb0c, Oe0, 0, 0, 0);
            Oe1 = __builtin_amdgcn_mfma_f32_16x16x32_bf16(ae, vb1c, Oe1, 0, 0, 0);
            Og0 = __builtin_amdgcn_mfma_f32_16x16x32_bf16(agc, vb0c, Og0, 0, 0, 0);
            Og1 = __builtin_amdgcn_mfma_f32_16x16x32_bf16(agc, vb1c, Og1, 0, 0, 0);
        }
        esum += __shfl_xor(esum, 16);
        esum += __shfl_xor(esum, 32);          // full row sum for query i0+li
        float ps = omg / esum;                 // (skip /attn.sum: it's 1 +- 1e-6)
        float psr[4];
#pragma unroll
        for (int r = 0; r < 4; ++r) psr[r] = __shfl(ps, qd * 4 + r);
#pragma unroll
        for (int r = 0; r < 4; ++r) {
            int row = i0 + qd * 4 + r;
            if (row < NSEQ) {
                int m = b * NSEQ + row;
                int rt = m >> 7, rr = m & 127;
                int c0 = (h & 1) * 4 + (li >> 3);
                int p2 = li & 7;
                size_t tb = ((size_t)(rt * 4 + (h >> 1)) * 128 + rr) * 64;
                ot[tb + ((c0 ^ (rr & 7)) * 8) + p2] = f2bf(fmaf(psr[r], Oe0[r], Og0[r]));
                ot[tb + (((c0 + 2) ^ (rr & 7)) * 8) + p2] = f2bf(fmaf(psr[r], Oe1[r], Og1[r]));
            }
        }
        q0 = q1; q1 = q2;                      // rotate q registers (static idx)
    }
}

// ---------------- K4: output projection, double-buffered, 1 barrier/step ----------------
__global__ __launch_bounds__(256, 3) void gemm_proj_mfma(
    const ushort* __restrict__ A, const ushort* __restrict__ Bw,
    const float* __restrict__ bias, float* __restrict__ out)
{
    __shared__ ushort smem[24576];    // 49152B: As x2 (8KB) + Bs x2 (32KB)
    ushort* As0 = smem;               // 64*64 = 4096 ushorts
    ushort* As1 = smem + 4096;
    ushort* Bs0 = smem + 8192;        // 128*64 = 8192 ushorts
    ushort* Bs1 = smem + 16384;
    int tid = threadIdx.x;
    int wave = tid >> 6, lane = tid & 63, li = lane & 15, qd = lane >> 4;
    int rh = wave >> 1, ch = wave & 1;
    int by = blockIdx.y;
    const ushort* gA = A + ((size_t)(by >> 1) * 4 * 128 + (by & 1) * 64) * 64;
    const ushort* gB = Bw + (size_t)blockIdx.x * 4 * 8192;

    v4f acc[2][4];
#pragma unroll
    for (int i = 0; i < 2; ++i)
#pragma unroll
        for (int j = 0; j < 4; ++j) acc[i][j] = (v4f){0.f, 0.f, 0.f, 0.f};

    auto issue_step = [&](int kt, ushort* as, ushort* bs) {
#pragma unroll
        for (int s = 0; s < 2; ++s) {
            int cch = s * 256 + tid;
            gl_lds16(gA + (size_t)kt * 8192 + cch * 8, as + cch * 8);
        }
#pragma unroll
        for (int s = 0; s < 4; ++s) {
            int cch = s * 256 + tid;
            gl_lds16(gB + (size_t)kt * 8192 + cch * 8, bs + cch * 8);
        }
    };

    issue_step(0, As0, Bs0);
#pragma unroll
    for (int kt = 0; kt < 4; ++kt) {
        __syncthreads();                       // drains DMA for buf[kt&1]
        if (kt < 3)
            issue_step(kt + 1, (kt & 1) ? As0 : As1, (kt & 1) ? Bs0 : Bs1);
        const ushort* as = (kt & 1) ? As1 : As0;
        const ushort* bs = (kt & 1) ? Bs1 : Bs0;
#pragma unroll
        for (int kc = 0; kc < 64; kc += 32) {
            int cb = (kc >> 3) + qd;
            int cs = cb ^ (li & 7);
            v8s a[2], b[4];
#pragma unroll
            for (int mt = 0; mt < 2; ++mt)
                a[mt] = *(const v8s*)&as[(rh * 32 + mt * 16 + li) * 64 + cs * 8];
#pragma unroll
            for (int nt = 0; nt < 4; ++nt)
                b[nt] = *(const v8s*)&bs[(ch * 64 + nt * 16 + li) * 64 + cs * 8];
#pragma unroll
            for (int mt = 0; mt < 2; ++mt)
#pragma unroll
                for (int nt = 0; nt < 4; ++nt)
                    acc[mt][nt] = __builtin_amdgcn_mfma_f32_16x16x32_bf16(b[nt], a[mt], acc[mt][nt], 0, 0, 0);
        }
    }

#pragma unroll
    for (int mt = 0; mt < 2; ++mt) {
        int row = by * 64 + rh * 32 + mt * 16 + li;
#pragma unroll
        for (int nt = 0; nt < 4; ++nt) {
            int col = blockIdx.x * 128 + ch * 64 + nt * 16 + qd * 4;
            float4 bv = *(const float4*)&bias[col];
            float4 st = {acc[mt][nt][0] + bv.x, acc[mt][nt][1] + bv.y,
                         acc[mt][nt][2] + bv.z, acc[mt][nt][3] + bv.w};
            *(float4*)&out[(size_t)row * 256 + col] = st;
        }
    }
}

extern "C" void kernel_launch(void* const* d_in, const int* in_sizes, int n_in,
                              void* d_out, int out_size, void* d_ws, size_t ws_size,
                              hipStream_t stream) {
    const float* x      = (const float*)d_in[0];
    const float* Wqk    = (const float*)d_in[1];
    const float* Wv     = (const float*)d_in[2];
    const float* Wpos   = (const float*)d_in[3];
    const float* bpos   = (const float*)d_in[4];
    const float* Wproj  = (const float*)d_in[5];
    const float* bproj  = (const float*)d_in[6];
    const float* gating = (const float*)d_in[7];
    float* out = (float*)d_out;

    ushort* gpos     = (ushort*)d_ws;             // 8*304*320 = 778,240 (pair-interleaved)
    ushort* Wf       = gpos + 778240;             // 8*8*96*32 = 196,608 (st-swizzled)
    ushort* wproj_t  = Wf + 196608;               // 65,536 (tiled+swizzled)
    ushort* o_t      = wproj_t + 65536;           // 4,915,200 (tiled+swizzled)
    ushort* x_bf     = o_t + 4915200;             // 64*304*256 = 4,980,736

    prep_kernel<<<3168, 256, 0, stream>>>(x, Wqk, Wv, Wproj, Wpos, bpos, gating,
                                          x_bf, Wf, wproj_t, gpos);
    fused_qkv_attn<<<512, 512, 0, stream>>>(x_bf, Wf, gpos, gating, o_t);
    gemm_proj_mfma<<<dim3(2, 300), 256, 0, stream>>>(o_t, wproj_t, bproj, out);
}